// Round 1
// baseline (2996.843 us; speedup 1.0000x reference)
//
#include <hip/hip_runtime.h>
#include <math.h>

#define C 256
#define DH 32
#define NH 8
#define NL 4
#define NP 4
#define BQ 4
#define LQ 900
#define LVTOT 17821
#define DFFN 2048
#define NTOK (BQ*LQ)          // 3600 token rows, token index t = lq*BQ + b

// ---------------- block reductions (256 threads, wave64) ----------------
__device__ __forceinline__ float block_sum256(float v, float* pr) {
    int t = threadIdx.x, lane = t & 63, wv = t >> 6;
#pragma unroll
    for (int o = 32; o > 0; o >>= 1) v += __shfl_down(v, o, 64);
    if (lane == 0) pr[wv] = v;
    __syncthreads();
    float r = pr[0] + pr[1] + pr[2] + pr[3];
    __syncthreads();
    return r;
}

__device__ __forceinline__ float block_max256(float v, float* pr) {
    int t = threadIdx.x, lane = t & 63, wv = t >> 6;
#pragma unroll
    for (int o = 32; o > 0; o >>= 1) v = fmaxf(v, __shfl_down(v, o, 64));
    if (lane == 0) pr[wv] = v;
    __syncthreads();
    float r = fmaxf(fmaxf(pr[0], pr[1]), fmaxf(pr[2], pr[3]));
    __syncthreads();
    return r;
}

// ---------------- generic multi-row GEMM: Y = act(X @ W^T + b) ----------------
enum { MODE_NORMAL = 0, MODE_RELU = 1, MODE_VALUE = 2, MODE_QKV = 3 };

template<int K, int OC, int ROWS, int MODE>
__global__ void k_rowgemm(const float* __restrict__ Xin, const float* __restrict__ W,
                          const float* __restrict__ bias, float* __restrict__ Y, int nrows) {
    __shared__ float xs[ROWS * K];
    int t = threadIdx.x;
    int r0 = blockIdx.x * ROWS;
    for (int idx = t; idx < ROWS * K; idx += 256) {
        int j = idx / K;
        int rr = r0 + j;
        xs[idx] = (rr < nrows) ? Xin[(size_t)rr * K + (idx - j * K)] : 0.f;
    }
    __syncthreads();
#pragma unroll 1
    for (int tile = 0; tile < OC / 256; ++tile) {
        int oc = tile * 256 + t;
        const float4* w4 = (const float4*)(W + (size_t)oc * K);
        float b0 = bias[oc];
        float accv[ROWS];
#pragma unroll
        for (int j = 0; j < ROWS; ++j) accv[j] = b0;
        for (int k = 0; k < K / 4; ++k) {
            float4 wv = w4[k];
#pragma unroll
            for (int j = 0; j < ROWS; ++j) {
                float4 xv = ((const float4*)xs)[j * (K / 4) + k];
                accv[j] += wv.x * xv.x + wv.y * xv.y + wv.z * xv.z + wv.w * xv.w;
            }
        }
#pragma unroll
        for (int j = 0; j < ROWS; ++j) {
            int r = r0 + j;
            if (r >= nrows) continue;
            float v = accv[j];
            if (MODE == MODE_NORMAL) {
                Y[(size_t)r * OC + oc] = v;
            } else if (MODE == MODE_RELU) {
                Y[(size_t)r * OC + oc] = fmaxf(v, 0.f);
            } else if (MODE == MODE_VALUE) {
                int lv = r >> 2, b = r & 3;       // memory row r = lv*B + b
                int h = oc >> 5, d = oc & 31;
                Y[(((size_t)b * NH + h) * LVTOT + lv) * DH + d] = v;
            } else { // MODE_QKV: Y is QKV base, contiguous Q|K|V each [B,H,LQ,DH]
                int lq = r >> 2, b = r & 3;       // token row r = lq*B + b
                int part = oc >> 8, cc = oc & 255;
                int h = cc >> 5, d = cc & 31;
                if (part == 0) v *= 0.17677669529663687f;  // 1/sqrt(32)
                Y[(size_t)part * (BQ * NH * LQ * DH) + (((size_t)b * NH + h) * LQ + lq) * DH + d] = v;
            }
        }
    }
}

// ---------------- off + aw projection with per-head softmax over 16 ----------------
__global__ void k_off_aw(const float* __restrict__ tgt,
                         const float* __restrict__ off_w, const float* __restrict__ off_b,
                         const float* __restrict__ aw_w, const float* __restrict__ aw_b,
                         float* __restrict__ off, float* __restrict__ aw) {
    int r = blockIdx.x;   // token row = lq*B + b (matches tgt layout)
    int t = threadIdx.x;
    __shared__ float xs[C];
    __shared__ float logits[128];
    xs[t] = tgt[(size_t)r * C + t];
    __syncthreads();
    {
        const float4* w4 = (const float4*)(off_w + (size_t)t * C);
        const float4* x4 = (const float4*)xs;
        float a = off_b[t];
#pragma unroll 4
        for (int k = 0; k < C / 4; ++k) {
            float4 wv = w4[k], xv = x4[k];
            a += wv.x * xv.x + wv.y * xv.y + wv.z * xv.z + wv.w * xv.w;
        }
        off[(size_t)r * C + t] = a;
    }
    if (t < 128) {
        const float4* w4 = (const float4*)(aw_w + (size_t)t * C);
        const float4* x4 = (const float4*)xs;
        float a = aw_b[t];
#pragma unroll 4
        for (int k = 0; k < C / 4; ++k) {
            float4 wv = w4[k], xv = x4[k];
            a += wv.x * xv.x + wv.y * xv.y + wv.z * xv.z + wv.w * xv.w;
        }
        logits[t] = a;
    }
    __syncthreads();
    if (t < 8) {  // one thread per head, softmax over 16
        float mx = -1e30f;
#pragma unroll
        for (int i = 0; i < 16; ++i) mx = fmaxf(mx, logits[t * 16 + i]);
        float e[16], s = 0.f;
#pragma unroll
        for (int i = 0; i < 16; ++i) { e[i] = expf(logits[t * 16 + i] - mx); s += e[i]; }
        float inv = 1.0f / s;
#pragma unroll
        for (int i = 0; i < 16; ++i) aw[(size_t)r * 128 + t * 16 + i] = e[i] * inv;
    }
}

// ---------------- deformable sampling ----------------
__global__ void k_sample(const float* __restrict__ trp, const float* __restrict__ off,
                         const float* __restrict__ aw, const float* __restrict__ value,
                         float* __restrict__ acc) {
    int r = blockIdx.x;              // token row = lq*B + b
    int lq = r >> 2, b = r & 3;
    int t = threadIdx.x;
    int h = t >> 5, d = t & 31;
    const int Hs[4] = {100, 50, 25, 13};
    const int Ws[4] = {134, 67, 34, 17};
    const int Ss[4] = {0, 13400, 16750, 17600};
    const float* offr = off + (size_t)r * C;
    const float* awr = aw + (size_t)r * 128;
    const float* vb = value + ((size_t)b * NH + h) * (size_t)LVTOT * DH;
    float a = 0.f;
#pragma unroll
    for (int l = 0; l < 4; ++l) {
        float rx = trp[((size_t)r * NL + l) * 2 + 0];
        float ry = trp[((size_t)r * NL + l) * 2 + 1];
        int Hl = Hs[l], Wl = Ws[l], s = Ss[l];
        float fW = (float)Wl, fH = (float)Hl;
#pragma unroll
        for (int p = 0; p < 4; ++p) {
            float ox = offr[((h * NL + l) * NP + p) * 2 + 0];
            float oy = offr[((h * NL + l) * NP + p) * 2 + 1];
            float w = awr[h * 16 + l * 4 + p];
            float x = (rx + ox / fW) * fW - 0.5f;
            float y = (ry + oy / fH) * fH - 0.5f;
            float x0 = floorf(x), y0 = floorf(y);
            float sum = 0.f;
#pragma unroll
            for (int dy = 0; dy < 2; ++dy) {
#pragma unroll
                for (int dx = 0; dx < 2; ++dx) {
                    float xi = x0 + dx, yi = y0 + dy;
                    float wgt = (1.0f - fabsf(x - xi)) * (1.0f - fabsf(y - yi));
                    bool valid = (xi >= 0.f) && (xi < fW) && (yi >= 0.f) && (yi < fH);
                    int xic = min(max((int)xi, 0), Wl - 1);
                    int yic = min(max((int)yi, 0), Hl - 1);
                    float v = vb[((size_t)s + yic * Wl + xic) * DH + d];
                    sum += (valid ? wgt : 0.f) * v;
                }
            }
            a += w * sum;
        }
    }
    acc[(size_t)r * C + h * DH + d] = a;
}

// ---------------- fused single-row proj + residual + LN ----------------
__global__ void k_proj_res_ln(const float* __restrict__ inrow, const float* __restrict__ resid,
                              const float* __restrict__ W, const float* __restrict__ bias,
                              const float* __restrict__ g, const float* __restrict__ be,
                              float* __restrict__ out) {
    __shared__ float xs[C];
    __shared__ float pr[4];
    int r = blockIdx.x, t = threadIdx.x;
    xs[t] = inrow[(size_t)r * C + t];
    __syncthreads();
    const float4* w4 = (const float4*)(W + (size_t)t * C);
    const float4* x4 = (const float4*)xs;
    float a = bias[t];
#pragma unroll 4
    for (int k = 0; k < C / 4; ++k) {
        float4 wv = w4[k], xv = x4[k];
        a += wv.x * xv.x + wv.y * xv.y + wv.z * xv.z + wv.w * xv.w;
    }
    float v = a + resid[(size_t)r * C + t];
    float mean = block_sum256(v, pr) * (1.0f / C);
    float dv = v - mean;
    float var = block_sum256(dv * dv, pr) * (1.0f / C);
    out[(size_t)r * C + t] = dv * rsqrtf(var + 1e-5f) * g[t] + be[t];
}

// ---------------- residual + LN only ----------------
__global__ void k_res_ln(const float* __restrict__ Yin, const float* __restrict__ Xres,
                         const float* __restrict__ g, const float* __restrict__ be,
                         float* __restrict__ out) {
    __shared__ float pr[4];
    int r = blockIdx.x, t = threadIdx.x;
    float v = Yin[(size_t)r * C + t] + Xres[(size_t)r * C + t];
    float mean = block_sum256(v, pr) * (1.0f / C);
    float dv = v - mean;
    float var = block_sum256(dv * dv, pr) * (1.0f / C);
    out[(size_t)r * C + t] = dv * rsqrtf(var + 1e-5f) * g[t] + be[t];
}

// ---------------- attention core: one block per (b,h,lq) ----------------
__global__ void k_attn(const float* __restrict__ Q, const float* __restrict__ K,
                       const float* __restrict__ V, float* __restrict__ O) {
    int n = blockIdx.x;           // (b*NH+h)*LQ + lq
    int bh = n / LQ, lq = n % LQ;
    int b = bh >> 3, h = bh & 7;
    int t = threadIdx.x;
    __shared__ float sc[LQ];
    __shared__ float qs[DH];
    __shared__ float pr[4];
    __shared__ float op[8][DH];
    if (t < DH) qs[t] = Q[((size_t)bh * LQ + lq) * DH + t];
    __syncthreads();
    float lmax = -1e30f;
    for (int m = t; m < LQ; m += 256) {
        const float* kr = K + ((size_t)bh * LQ + m) * DH;
        float s = 0.f;
#pragma unroll
        for (int k = 0; k < DH; ++k) s += qs[k] * kr[k];
        sc[m] = s;
        lmax = fmaxf(lmax, s);
    }
    float mx = block_max256(lmax, pr);
    float lsum = 0.f;
    for (int m = t; m < LQ; m += 256) {
        float e = expf(sc[m] - mx);
        sc[m] = e;
        lsum += e;
    }
    float ssum = block_sum256(lsum, pr);
    float inv = 1.0f / ssum;
    int d = t & 31, chunk = t >> 5;
    float part = 0.f;
    for (int m = chunk; m < LQ; m += 8) {
        part += sc[m] * V[((size_t)bh * LQ + m) * DH + d];
    }
    op[chunk][d] = part;
    __syncthreads();
    if (chunk == 0) {
        float o = 0.f;
#pragma unroll
        for (int cc = 0; cc < 8; ++cc) o += op[cc][d];
        o *= inv;
        // store in token layout [lq*B+b, C]
        O[((size_t)(lq * BQ + b)) * C + h * DH + d] = o;
    }
}

// ---------------- launch ----------------
extern "C" void kernel_launch(void* const* d_in, const int* in_sizes, int n_in,
                              void* d_out, int out_size, void* d_ws, size_t ws_size,
                              hipStream_t stream) {
    const float* tgt      = (const float*)d_in[0];
    const float* trp      = (const float*)d_in[1];
    const float* memory   = (const float*)d_in[2];
    // d_in[3] spatial shapes, d_in[4] level starts: compile-time constants
    const float* vproj_w  = (const float*)d_in[5];  const float* vproj_b  = (const float*)d_in[6];
    const float* off_w    = (const float*)d_in[7];  const float* off_b    = (const float*)d_in[8];
    const float* aw_w     = (const float*)d_in[9];  const float* aw_b     = (const float*)d_in[10];
    const float* oproj_w  = (const float*)d_in[11]; const float* oproj_b  = (const float*)d_in[12];
    const float* ln1_g    = (const float*)d_in[13]; const float* ln1_b    = (const float*)d_in[14];
    const float* sa_in_w  = (const float*)d_in[15]; const float* sa_in_b  = (const float*)d_in[16];
    const float* sa_out_w = (const float*)d_in[17]; const float* sa_out_b = (const float*)d_in[18];
    const float* ln2_g    = (const float*)d_in[19]; const float* ln2_b    = (const float*)d_in[20];
    const float* l1_w     = (const float*)d_in[21]; const float* l1_b     = (const float*)d_in[22];
    const float* l2_w     = (const float*)d_in[23]; const float* l2_b     = (const float*)d_in[24];
    const float* ln3_g    = (const float*)d_in[25]; const float* ln3_b    = (const float*)d_in[26];
    const float* sa3_in_w = (const float*)d_in[27]; const float* sa3_in_b = (const float*)d_in[28];
    const float* sa3_out_w= (const float*)d_in[29]; const float* sa3_out_b= (const float*)d_in[30];
    const float* ln5_g    = (const float*)d_in[31]; const float* ln5_b    = (const float*)d_in[32];
    const float* l31_w    = (const float*)d_in[33]; const float* l31_b    = (const float*)d_in[34];
    const float* l32_w    = (const float*)d_in[35]; const float* l32_b    = (const float*)d_in[36];
    const float* ln33_g   = (const float*)d_in[37]; const float* ln33_b   = (const float*)d_in[38];

    float* ws = (float*)d_ws;
    float* X     = ws;                       // 921,600  (current residual stream, token layout)
    float* value = ws + 921600;              // 18,248,704  [B,H,LV,32]
    float* off   = value + 18248704;         // 921,600
    float* aw    = off + 921600;             // 460,800
    float* acc   = aw + 460800;              // 921,600
    // value region reused after cross-attn:
    float* QKV = value;                      // 2,764,800 (Q|K|V each 921,600)
    float* O   = value + 2764800;            // 921,600
    float* H1  = value + 3686400;            // 7,372,800
    float* Y   = value + 11059200;           // 921,600

    const int NVROWS = BQ * LVTOT;           // 71,284
    dim3 blk(256);

    // ---- ca: MSDeformAttn ----
    k_rowgemm<256, 256, 8, MODE_VALUE><<<(NVROWS + 7) / 8, blk, 0, stream>>>(memory, vproj_w, vproj_b, value, NVROWS);
    k_off_aw<<<NTOK, blk, 0, stream>>>(tgt, off_w, off_b, aw_w, aw_b, off, aw);
    k_sample<<<NTOK, blk, 0, stream>>>(trp, off, aw, value, acc);
    k_proj_res_ln<<<NTOK, blk, 0, stream>>>(acc, tgt, oproj_w, oproj_b, ln1_g, ln1_b, X);

    // ---- sa ----
    k_rowgemm<256, 768, 8, MODE_QKV><<<NTOK / 8, blk, 0, stream>>>(X, sa_in_w, sa_in_b, QKV, NTOK);
    k_attn<<<BQ * NH * LQ, blk, 0, stream>>>(QKV, QKV + 921600, QKV + 1843200, O);
    k_proj_res_ln<<<NTOK, blk, 0, stream>>>(O, X, sa_out_w, sa_out_b, ln2_g, ln2_b, X);

    // ---- ffn ----
    k_rowgemm<256, 2048, 8, MODE_RELU><<<NTOK / 8, blk, 0, stream>>>(X, l1_w, l1_b, H1, NTOK);
    k_rowgemm<2048, 256, 4, MODE_NORMAL><<<NTOK / 4, blk, 0, stream>>>(H1, l2_w, l2_b, Y, NTOK);
    k_res_ln<<<NTOK, blk, 0, stream>>>(Y, X, ln3_g, ln3_b, X);

    // ---- sa3 ----
    k_rowgemm<256, 768, 8, MODE_QKV><<<NTOK / 8, blk, 0, stream>>>(X, sa3_in_w, sa3_in_b, QKV, NTOK);
    k_attn<<<BQ * NH * LQ, blk, 0, stream>>>(QKV, QKV + 921600, QKV + 1843200, O);
    k_proj_res_ln<<<NTOK, blk, 0, stream>>>(O, X, sa3_out_w, sa3_out_b, ln5_g, ln5_b, X);

    // ---- ffn3 ----
    k_rowgemm<256, 2048, 8, MODE_RELU><<<NTOK / 8, blk, 0, stream>>>(X, l31_w, l31_b, H1, NTOK);
    k_rowgemm<2048, 256, 4, MODE_NORMAL><<<NTOK / 4, blk, 0, stream>>>(H1, l32_w, l32_b, Y, NTOK);
    k_res_ln<<<NTOK, blk, 0, stream>>>(Y, X, ln33_g, ln33_b, (float*)d_out);
}

// Round 2
// 2128.847 us; speedup vs baseline: 1.4077x; 1.4077x over previous
//
#include <hip/hip_runtime.h>
#include <math.h>

#define C 256
#define DH 32
#define NH 8
#define NL 4
#define NP 4
#define BQ 4
#define LQ 900
#define LVTOT 17821
#define DFFN 2048
#define NTOK (BQ*LQ)          // 3600 token rows, token index t = lq*BQ + b

// ---------------- block reductions (256 threads, wave64) ----------------
__device__ __forceinline__ float block_sum256(float v, float* pr) {
    int t = threadIdx.x, lane = t & 63, wv = t >> 6;
#pragma unroll
    for (int o = 32; o > 0; o >>= 1) v += __shfl_down(v, o, 64);
    if (lane == 0) pr[wv] = v;
    __syncthreads();
    float r = pr[0] + pr[1] + pr[2] + pr[3];
    __syncthreads();
    return r;
}

// ---------------- generic multi-row GEMM: Y = act(X @ W^T + b) ----------------
enum { MODE_NORMAL = 0, MODE_RELU = 1, MODE_VALUE = 2, MODE_QKV = 3 };

template<int K, int OC, int ROWS, int MODE>
__global__ void k_rowgemm(const float* __restrict__ Xin, const float* __restrict__ W,
                          const float* __restrict__ bias, float* __restrict__ Y, int nrows) {
    __shared__ float xs[ROWS * K];
    int t = threadIdx.x;
    int r0 = blockIdx.x * ROWS;
    for (int idx = t; idx < ROWS * K; idx += 256) {
        int j = idx / K;
        int rr = r0 + j;
        xs[idx] = (rr < nrows) ? Xin[(size_t)rr * K + (idx - j * K)] : 0.f;
    }
    __syncthreads();
#pragma unroll 1
    for (int tile = 0; tile < OC / 256; ++tile) {
        int oc = tile * 256 + t;
        const float4* w4 = (const float4*)(W + (size_t)oc * K);
        float b0 = bias[oc];
        float accv[ROWS];
#pragma unroll
        for (int j = 0; j < ROWS; ++j) accv[j] = b0;
        for (int k = 0; k < K / 4; ++k) {
            float4 wv = w4[k];
#pragma unroll
            for (int j = 0; j < ROWS; ++j) {
                float4 xv = ((const float4*)xs)[j * (K / 4) + k];
                accv[j] += wv.x * xv.x + wv.y * xv.y + wv.z * xv.z + wv.w * xv.w;
            }
        }
#pragma unroll
        for (int j = 0; j < ROWS; ++j) {
            int r = r0 + j;
            if (r >= nrows) continue;
            float v = accv[j];
            if (MODE == MODE_NORMAL) {
                Y[(size_t)r * OC + oc] = v;
            } else if (MODE == MODE_RELU) {
                Y[(size_t)r * OC + oc] = fmaxf(v, 0.f);
            } else if (MODE == MODE_VALUE) {
                int lv = r >> 2, b = r & 3;       // memory row r = lv*B + b
                int h = oc >> 5, d = oc & 31;
                Y[(((size_t)b * NH + h) * LVTOT + lv) * DH + d] = v;
            } else { // MODE_QKV: Y is QKV base, contiguous Q|K|V each [B,H,LQ,DH]
                int lq = r >> 2, b = r & 3;       // token row r = lq*B + b
                int part = oc >> 8, cc = oc & 255;
                int h = cc >> 5, d = cc & 31;
                if (part == 0) v *= 0.17677669529663687f;  // 1/sqrt(32)
                Y[(size_t)part * (BQ * NH * LQ * DH) + (((size_t)b * NH + h) * LQ + lq) * DH + d] = v;
            }
        }
    }
}

// ---------------- off + aw projection with per-head softmax over 16 ----------------
__global__ void k_off_aw(const float* __restrict__ tgt,
                         const float* __restrict__ off_w, const float* __restrict__ off_b,
                         const float* __restrict__ aw_w, const float* __restrict__ aw_b,
                         float* __restrict__ off, float* __restrict__ aw) {
    int r = blockIdx.x;   // token row = lq*B + b (matches tgt layout)
    int t = threadIdx.x;
    __shared__ float xs[C];
    __shared__ float logits[128];
    xs[t] = tgt[(size_t)r * C + t];
    __syncthreads();
    {
        const float4* w4 = (const float4*)(off_w + (size_t)t * C);
        const float4* x4 = (const float4*)xs;
        float a = off_b[t];
#pragma unroll 4
        for (int k = 0; k < C / 4; ++k) {
            float4 wv = w4[k], xv = x4[k];
            a += wv.x * xv.x + wv.y * xv.y + wv.z * xv.z + wv.w * xv.w;
        }
        off[(size_t)r * C + t] = a;
    }
    if (t < 128) {
        const float4* w4 = (const float4*)(aw_w + (size_t)t * C);
        const float4* x4 = (const float4*)xs;
        float a = aw_b[t];
#pragma unroll 4
        for (int k = 0; k < C / 4; ++k) {
            float4 wv = w4[k], xv = x4[k];
            a += wv.x * xv.x + wv.y * xv.y + wv.z * xv.z + wv.w * xv.w;
        }
        logits[t] = a;
    }
    __syncthreads();
    if (t < 8) {  // one thread per head, softmax over 16
        float mx = -1e30f;
#pragma unroll
        for (int i = 0; i < 16; ++i) mx = fmaxf(mx, logits[t * 16 + i]);
        float e[16], s = 0.f;
#pragma unroll
        for (int i = 0; i < 16; ++i) { e[i] = expf(logits[t * 16 + i] - mx); s += e[i]; }
        float inv = 1.0f / s;
#pragma unroll
        for (int i = 0; i < 16; ++i) aw[(size_t)r * 128 + t * 16 + i] = e[i] * inv;
    }
}

// ---------------- deformable sampling ----------------
__global__ void k_sample(const float* __restrict__ trp, const float* __restrict__ off,
                         const float* __restrict__ aw, const float* __restrict__ value,
                         float* __restrict__ acc) {
    int r = blockIdx.x;              // token row = lq*B + b
    int lq = r >> 2, b = r & 3;
    (void)lq;
    int t = threadIdx.x;
    int h = t >> 5, d = t & 31;
    const int Hs[4] = {100, 50, 25, 13};
    const int Ws[4] = {134, 67, 34, 17};
    const int Ss[4] = {0, 13400, 16750, 17600};
    const float* offr = off + (size_t)r * C;
    const float* awr = aw + (size_t)r * 128;
    const float* vb = value + ((size_t)b * NH + h) * (size_t)LVTOT * DH;
    float a = 0.f;
#pragma unroll
    for (int l = 0; l < 4; ++l) {
        float rx = trp[((size_t)r * NL + l) * 2 + 0];
        float ry = trp[((size_t)r * NL + l) * 2 + 1];
        int Hl = Hs[l], Wl = Ws[l], s = Ss[l];
        float fW = (float)Wl, fH = (float)Hl;
#pragma unroll
        for (int p = 0; p < 4; ++p) {
            float ox = offr[((h * NL + l) * NP + p) * 2 + 0];
            float oy = offr[((h * NL + l) * NP + p) * 2 + 1];
            float w = awr[h * 16 + l * 4 + p];
            float x = (rx + ox / fW) * fW - 0.5f;
            float y = (ry + oy / fH) * fH - 0.5f;
            float x0 = floorf(x), y0 = floorf(y);
            float sum = 0.f;
#pragma unroll
            for (int dy = 0; dy < 2; ++dy) {
#pragma unroll
                for (int dx = 0; dx < 2; ++dx) {
                    float xi = x0 + dx, yi = y0 + dy;
                    float wgt = (1.0f - fabsf(x - xi)) * (1.0f - fabsf(y - yi));
                    bool valid = (xi >= 0.f) && (xi < fW) && (yi >= 0.f) && (yi < fH);
                    int xic = min(max((int)xi, 0), Wl - 1);
                    int yic = min(max((int)yi, 0), Hl - 1);
                    float v = vb[((size_t)s + yic * Wl + xic) * DH + d];
                    sum += (valid ? wgt : 0.f) * v;
                }
            }
            a += w * sum;
        }
    }
    acc[(size_t)r * C + h * DH + d] = a;
}

// ---------------- fused single-row proj + residual + LN ----------------
__global__ void k_proj_res_ln(const float* __restrict__ inrow, const float* __restrict__ resid,
                              const float* __restrict__ W, const float* __restrict__ bias,
                              const float* __restrict__ g, const float* __restrict__ be,
                              float* __restrict__ out) {
    __shared__ float xs[C];
    __shared__ float pr[4];
    int r = blockIdx.x, t = threadIdx.x;
    xs[t] = inrow[(size_t)r * C + t];
    __syncthreads();
    const float4* w4 = (const float4*)(W + (size_t)t * C);
    const float4* x4 = (const float4*)xs;
    float a = bias[t];
#pragma unroll 4
    for (int k = 0; k < C / 4; ++k) {
        float4 wv = w4[k], xv = x4[k];
        a += wv.x * xv.x + wv.y * xv.y + wv.z * xv.z + wv.w * xv.w;
    }
    float v = a + resid[(size_t)r * C + t];
    float mean = block_sum256(v, pr) * (1.0f / C);
    float dv = v - mean;
    float var = block_sum256(dv * dv, pr) * (1.0f / C);
    out[(size_t)r * C + t] = dv * rsqrtf(var + 1e-5f) * g[t] + be[t];
}

// ---------------- residual + LN only ----------------
__global__ void k_res_ln(const float* __restrict__ Yin, const float* __restrict__ Xres,
                         const float* __restrict__ g, const float* __restrict__ be,
                         float* __restrict__ out) {
    __shared__ float pr[4];
    int r = blockIdx.x, t = threadIdx.x;
    float v = Yin[(size_t)r * C + t] + Xres[(size_t)r * C + t];
    float mean = block_sum256(v, pr) * (1.0f / C);
    float dv = v - mean;
    float var = block_sum256(dv * dv, pr) * (1.0f / C);
    out[(size_t)r * C + t] = dv * rsqrtf(var + 1e-5f) * g[t] + be[t];
}

// ---------------- flash attention: one block per (b,h, 32-query tile) ----------------
#define TQ 32
#define MK 64
#define KST 36            // padded K/V row stride (floats): conflict-free score reads
#define NCHUNK ((LQ + TQ - 1) / TQ)   // 29

__global__ void k_attn2(const float* __restrict__ Q, const float* __restrict__ K,
                        const float* __restrict__ V, float* __restrict__ O) {
    __shared__ float Ks[MK][KST];
    __shared__ float Vs[MK][KST];
    int blk = blockIdx.x;
    int bh = blk / NCHUNK;
    int q0 = (blk % NCHUNK) * TQ;
    int b = bh >> 3, h = bh & 7;
    int t = threadIdx.x;
    int q = t >> 3;          // 0..31 local query
    int kg = t & 7;          // 0..7 key group / d-group
    int d0 = kg * 4;

    const float* Qb = Q + (size_t)bh * LQ * DH;
    const float* Kb = K + (size_t)bh * LQ * DH;
    const float* Vb = V + (size_t)bh * LQ * DH;

    // Q row for this thread's query, in registers (clamped row for OOB q; store guarded)
    int qglob = q0 + q;
    const float* qrow = Qb + (size_t)min(qglob, LQ - 1) * DH;
    float4 qreg[8];
#pragma unroll
    for (int i = 0; i < 8; ++i) qreg[i] = *(const float4*)(qrow + i * 4);

    float m = -1e30f, l = 0.f;
    float acc[4] = {0.f, 0.f, 0.f, 0.f};

    for (int k0 = 0; k0 < LQ; k0 += MK) {
        __syncthreads();   // previous chunk fully consumed before overwrite
        // stage K,V chunk: each thread loads one float4 of K and one of V, twice
#pragma unroll
        for (int rep = 0; rep < 2; ++rep) {
            int i = rep * 256 + t;
            int kk = i >> 3, dd = (i & 7) * 4;
            int kglob = k0 + kk;
            float4 kv, vv;
            if (kglob < LQ) {
                kv = *(const float4*)(Kb + (size_t)kglob * DH + dd);
                vv = *(const float4*)(Vb + (size_t)kglob * DH + dd);
            } else {
                kv = make_float4(0.f, 0.f, 0.f, 0.f);
                vv = make_float4(0.f, 0.f, 0.f, 0.f);
            }
            *(float4*)(&Ks[kk][dd]) = kv;
            *(float4*)(&Vs[kk][dd]) = vv;
        }
        __syncthreads();

        // scores for keys kk = kg + 8j
        float sv[8];
        float cmax = -1e30f;
#pragma unroll
        for (int j = 0; j < 8; ++j) {
            int kk = kg + 8 * j;
            float s = 0.f;
#pragma unroll
            for (int i = 0; i < 8; ++i) {
                float4 kv = *(const float4*)(&Ks[kk][i * 4]);
                s += qreg[i].x * kv.x + qreg[i].y * kv.y + qreg[i].z * kv.z + qreg[i].w * kv.w;
            }
            bool valid = (k0 + kk) < LQ;
            s = valid ? s : -1e30f;
            sv[j] = s;
            cmax = fmaxf(cmax, s);
        }
#pragma unroll
        for (int o = 1; o < 8; o <<= 1) cmax = fmaxf(cmax, __shfl_xor(cmax, o, 8));
        float mnew = fmaxf(m, cmax);
        float scale = expf(m - mnew);
        float csum = 0.f;
#pragma unroll
        for (int j = 0; j < 8; ++j) {
            float e = (sv[j] > -1e29f) ? expf(sv[j] - mnew) : 0.f;
            sv[j] = e;
            csum += e;
        }
#pragma unroll
        for (int o = 1; o < 8; o <<= 1) csum += __shfl_xor(csum, o, 8);
        l = l * scale + csum;
        m = mnew;

        // PV: acc over 64 keys; p shared via shfl within the 8-lane q-group
        acc[0] *= scale; acc[1] *= scale; acc[2] *= scale; acc[3] *= scale;
#pragma unroll
        for (int j = 0; j < 8; ++j) {
#pragma unroll
            for (int i = 0; i < 8; ++i) {
                int kk = j * 8 + i;
                float p = __shfl(sv[j], i, 8);
                float4 vv = *(const float4*)(&Vs[kk][d0]);
                acc[0] += p * vv.x; acc[1] += p * vv.y; acc[2] += p * vv.z; acc[3] += p * vv.w;
            }
        }
    }

    if (qglob < LQ) {
        float inv = 1.0f / l;
        int lq = qglob;
        float* o = O + ((size_t)(lq * BQ + b)) * C + h * DH + d0;
        o[0] = acc[0] * inv; o[1] = acc[1] * inv; o[2] = acc[2] * inv; o[3] = acc[3] * inv;
    }
}

// ---------------- launch ----------------
extern "C" void kernel_launch(void* const* d_in, const int* in_sizes, int n_in,
                              void* d_out, int out_size, void* d_ws, size_t ws_size,
                              hipStream_t stream) {
    const float* tgt      = (const float*)d_in[0];
    const float* trp      = (const float*)d_in[1];
    const float* memory   = (const float*)d_in[2];
    const float* vproj_w  = (const float*)d_in[5];  const float* vproj_b  = (const float*)d_in[6];
    const float* off_w    = (const float*)d_in[7];  const float* off_b    = (const float*)d_in[8];
    const float* aw_w     = (const float*)d_in[9];  const float* aw_b     = (const float*)d_in[10];
    const float* oproj_w  = (const float*)d_in[11]; const float* oproj_b  = (const float*)d_in[12];
    const float* ln1_g    = (const float*)d_in[13]; const float* ln1_b    = (const float*)d_in[14];
    const float* sa_in_w  = (const float*)d_in[15]; const float* sa_in_b  = (const float*)d_in[16];
    const float* sa_out_w = (const float*)d_in[17]; const float* sa_out_b = (const float*)d_in[18];
    const float* ln2_g    = (const float*)d_in[19]; const float* ln2_b    = (const float*)d_in[20];
    const float* l1_w     = (const float*)d_in[21]; const float* l1_b     = (const float*)d_in[22];
    const float* l2_w     = (const float*)d_in[23]; const float* l2_b     = (const float*)d_in[24];
    const float* ln3_g    = (const float*)d_in[25]; const float* ln3_b    = (const float*)d_in[26];
    const float* sa3_in_w = (const float*)d_in[27]; const float* sa3_in_b = (const float*)d_in[28];
    const float* sa3_out_w= (const float*)d_in[29]; const float* sa3_out_b= (const float*)d_in[30];
    const float* ln5_g    = (const float*)d_in[31]; const float* ln5_b    = (const float*)d_in[32];
    const float* l31_w    = (const float*)d_in[33]; const float* l31_b    = (const float*)d_in[34];
    const float* l32_w    = (const float*)d_in[35]; const float* l32_b    = (const float*)d_in[36];
    const float* ln33_g   = (const float*)d_in[37]; const float* ln33_b   = (const float*)d_in[38];

    float* ws = (float*)d_ws;
    float* X     = ws;                       // 921,600  (current residual stream, token layout)
    float* value = ws + 921600;              // 18,248,704  [B,H,LV,32]
    float* off   = value + 18248704;         // 921,600
    float* aw    = off + 921600;             // 460,800
    float* acc   = aw + 460800;              // 921,600
    // value region reused after cross-attn:
    float* QKV = value;                      // 2,764,800 (Q|K|V each 921,600)
    float* O   = value + 2764800;            // 921,600
    float* H1  = value + 3686400;            // 7,372,800
    float* Y   = value + 11059200;           // 921,600

    const int NVROWS = BQ * LVTOT;           // 71,284
    dim3 blk(256);

    // ---- ca: MSDeformAttn ----
    k_rowgemm<256, 256, 8, MODE_VALUE><<<(NVROWS + 7) / 8, blk, 0, stream>>>(memory, vproj_w, vproj_b, value, NVROWS);
    k_off_aw<<<NTOK, blk, 0, stream>>>(tgt, off_w, off_b, aw_w, aw_b, off, aw);
    k_sample<<<NTOK, blk, 0, stream>>>(trp, off, aw, value, acc);
    k_proj_res_ln<<<NTOK, blk, 0, stream>>>(acc, tgt, oproj_w, oproj_b, ln1_g, ln1_b, X);

    // ---- sa ----
    k_rowgemm<256, 768, 8, MODE_QKV><<<NTOK / 8, blk, 0, stream>>>(X, sa_in_w, sa_in_b, QKV, NTOK);
    k_attn2<<<BQ * NH * NCHUNK, blk, 0, stream>>>(QKV, QKV + 921600, QKV + 1843200, O);
    k_proj_res_ln<<<NTOK, blk, 0, stream>>>(O, X, sa_out_w, sa_out_b, ln2_g, ln2_b, X);

    // ---- ffn ----
    k_rowgemm<256, 2048, 8, MODE_RELU><<<NTOK / 8, blk, 0, stream>>>(X, l1_w, l1_b, H1, NTOK);
    k_rowgemm<2048, 256, 4, MODE_NORMAL><<<NTOK / 4, blk, 0, stream>>>(H1, l2_w, l2_b, Y, NTOK);
    k_res_ln<<<NTOK, blk, 0, stream>>>(Y, X, ln3_g, ln3_b, X);

    // ---- sa3 ----
    k_rowgemm<256, 768, 8, MODE_QKV><<<NTOK / 8, blk, 0, stream>>>(X, sa3_in_w, sa3_in_b, QKV, NTOK);
    k_attn2<<<BQ * NH * NCHUNK, blk, 0, stream>>>(QKV, QKV + 921600, QKV + 1843200, O);
    k_proj_res_ln<<<NTOK, blk, 0, stream>>>(O, X, sa3_out_w, sa3_out_b, ln5_g, ln5_b, X);

    // ---- ffn3 ----
    k_rowgemm<256, 2048, 8, MODE_RELU><<<NTOK / 8, blk, 0, stream>>>(X, l31_w, l31_b, H1, NTOK);
    k_rowgemm<2048, 256, 4, MODE_NORMAL><<<NTOK / 4, blk, 0, stream>>>(H1, l32_w, l32_b, Y, NTOK);
    k_res_ln<<<NTOK, blk, 0, stream>>>(Y, X, ln33_g, ln33_b, (float*)d_out);
}

// Round 4
// 1198.603 us; speedup vs baseline: 2.5003x; 1.7761x over previous
//
#include <hip/hip_runtime.h>
#include <math.h>

#define C 256
#define DH 32
#define NH 8
#define NL 4
#define NP 4
#define BQ 4
#define LQ 900
#define LVTOT 17821
#define DFFN 2048
#define NTOK (BQ*LQ)          // 3600 token rows, token index t = lq*B + b

typedef __attribute__((ext_vector_type(8))) short bf8_t;    // 8 bf16 (4 VGPRs)
typedef __attribute__((ext_vector_type(4))) float f4_t;     // MFMA acc
typedef __attribute__((ext_vector_type(8))) unsigned short us8_t;

// ---------------- block reductions (256 threads, wave64) ----------------
__device__ __forceinline__ float block_sum256(float v, float* pr) {
    int t = threadIdx.x, lane = t & 63, wv = t >> 6;
#pragma unroll
    for (int o = 32; o > 0; o >>= 1) v += __shfl_down(v, o, 64);
    if (lane == 0) pr[wv] = v;
    __syncthreads();
    float r = pr[0] + pr[1] + pr[2] + pr[3];
    __syncthreads();
    return r;
}

__device__ __forceinline__ unsigned short f2bf(float f) {
    unsigned int u = __float_as_uint(f);
    u += 0x7fffu + ((u >> 16) & 1u);   // round-to-nearest-even
    return (unsigned short)(u >> 16);
}

// ---------------- bf16 MFMA GEMM: Y = act(A @ W^T + b) ----------------
// A: [nrows][K] fp32 row-major; W: [OC][K] fp32 row-major (= B^T layout).
// Block tile 128(M) x 64(N), 4 waves in 2x2, K-step 32. fp32 staged -> bf16 LDS.
enum { MODE_NORMAL = 0, MODE_RELU = 1, MODE_VALUE = 2, MODE_QKV = 3 };

#define LDP 72   // LDS row stride in bf16 elems (144 B = 9*16B: aligned b128, conflict-free)

template<int K, int MODE>
__global__ void k_mgemm(const float* __restrict__ A, const float* __restrict__ W,
                        const float* __restrict__ bias, float* __restrict__ Y, int nrows) {
    __shared__ unsigned short Ash[128 * LDP];
    __shared__ unsigned short Bsh[64 * LDP];
    int t = threadIdx.x;
    int lane = t & 63, w = t >> 6;
    int wm = w & 1, wn = w >> 1;
    int r0 = blockIdx.x * 128;
    int c0 = blockIdx.y * 64;

    f4_t acc[4][2];
#pragma unroll
    for (int mt = 0; mt < 4; ++mt)
#pragma unroll
        for (int nt = 0; nt < 2; ++nt) acc[mt][nt] = (f4_t)0.f;

    // staging geometry
    int arow = t >> 1;                 // 0..127
    int akoff = (t & 1) * 16;          // 0 or 16
    int asrc = min(r0 + arow, nrows - 1);
    const float* aptr = A + (size_t)asrc * K + akoff;
    unsigned short* adst = &Ash[arow * LDP + akoff];

    int brow = t >> 2;                 // 0..63
    int bkoff = (t & 3) * 8;
    const float* bptr = W + (size_t)(c0 + brow) * K + bkoff;
    unsigned short* bdst = &Bsh[brow * LDP + bkoff];

    int lr = lane & 15, kg = lane >> 4;

    for (int k0 = 0; k0 < K; k0 += 32) {
        __syncthreads();
        // stage A: 16 floats -> 16 bf16 (two 16B LDS writes)
        {
            float4 av0 = *(const float4*)(aptr + k0);
            float4 av1 = *(const float4*)(aptr + k0 + 4);
            float4 av2 = *(const float4*)(aptr + k0 + 8);
            float4 av3 = *(const float4*)(aptr + k0 + 12);
            us8_t u0, u1;
            u0[0]=f2bf(av0.x); u0[1]=f2bf(av0.y); u0[2]=f2bf(av0.z); u0[3]=f2bf(av0.w);
            u0[4]=f2bf(av1.x); u0[5]=f2bf(av1.y); u0[6]=f2bf(av1.z); u0[7]=f2bf(av1.w);
            u1[0]=f2bf(av2.x); u1[1]=f2bf(av2.y); u1[2]=f2bf(av2.z); u1[3]=f2bf(av2.w);
            u1[4]=f2bf(av3.x); u1[5]=f2bf(av3.y); u1[6]=f2bf(av3.z); u1[7]=f2bf(av3.w);
            *(us8_t*)(adst) = u0;
            *(us8_t*)(adst + 8) = u1;
        }
        // stage B: 8 floats -> 8 bf16 (one 16B LDS write)
        {
            float4 bv0 = *(const float4*)(bptr + k0);
            float4 bv1 = *(const float4*)(bptr + k0 + 4);
            us8_t u;
            u[0]=f2bf(bv0.x); u[1]=f2bf(bv0.y); u[2]=f2bf(bv0.z); u[3]=f2bf(bv0.w);
            u[4]=f2bf(bv1.x); u[5]=f2bf(bv1.y); u[6]=f2bf(bv1.z); u[7]=f2bf(bv1.w);
            *(us8_t*)(bdst) = u;
        }
        __syncthreads();

        bf8_t afr[4], bfr[2];
#pragma unroll
        for (int mt = 0; mt < 4; ++mt)
            afr[mt] = *(const bf8_t*)&Ash[(wm * 64 + mt * 16 + lr) * LDP + kg * 8];
#pragma unroll
        for (int nt = 0; nt < 2; ++nt)
            bfr[nt] = *(const bf8_t*)&Bsh[(wn * 32 + nt * 16 + lr) * LDP + kg * 8];
#pragma unroll
        for (int mt = 0; mt < 4; ++mt)
#pragma unroll
            for (int nt = 0; nt < 2; ++nt)
                acc[mt][nt] = __builtin_amdgcn_mfma_f32_16x16x32_bf16(afr[mt], bfr[nt], acc[mt][nt], 0, 0, 0);
    }

    // epilogue
#pragma unroll
    for (int mt = 0; mt < 4; ++mt) {
#pragma unroll
        for (int nt = 0; nt < 2; ++nt) {
            int col = c0 + wn * 32 + nt * 16 + lr;
            float b0 = bias[col];
#pragma unroll
            for (int rr = 0; rr < 4; ++rr) {
                int row = r0 + wm * 64 + mt * 16 + kg * 4 + rr;
                if (row >= nrows) continue;
                float v = acc[mt][nt][rr] + b0;
                if (MODE == MODE_NORMAL) {
                    Y[(size_t)row * gridDim.y * 64 + col] = v;
                } else if (MODE == MODE_RELU) {
                    Y[(size_t)row * gridDim.y * 64 + col] = fmaxf(v, 0.f);
                } else if (MODE == MODE_VALUE) {
                    int lv = row >> 2, b = row & 3;      // memory row = lv*B + b
                    int h = col >> 5, d = col & 31;
                    Y[(((size_t)b * NH + h) * LVTOT + lv) * DH + d] = v;
                } else { // MODE_QKV
                    int lq = row >> 2, b = row & 3;      // token row = lq*B + b
                    int part = col >> 8, cc = col & 255;
                    int h = cc >> 5, d = cc & 31;
                    if (part == 0) v *= 0.17677669529663687f;  // 1/sqrt(32)
                    Y[(size_t)part * (BQ * NH * LQ * DH) + (((size_t)b * NH + h) * LQ + lq) * DH + d] = v;
                }
            }
        }
    }
}

// ---------------- off + aw projection with per-head softmax over 16 ----------------
__global__ void k_off_aw(const float* __restrict__ tgt,
                         const float* __restrict__ off_w, const float* __restrict__ off_b,
                         const float* __restrict__ aw_w, const float* __restrict__ aw_b,
                         float* __restrict__ off, float* __restrict__ aw) {
    int r = blockIdx.x;   // token row = lq*B + b (matches tgt layout)
    int t = threadIdx.x;
    __shared__ float xs[C];
    __shared__ float logits[128];
    xs[t] = tgt[(size_t)r * C + t];
    __syncthreads();
    {
        const float4* w4 = (const float4*)(off_w + (size_t)t * C);
        const float4* x4 = (const float4*)xs;
        float a = off_b[t];
#pragma unroll 4
        for (int k = 0; k < C / 4; ++k) {
            float4 wv = w4[k], xv = x4[k];
            a += wv.x * xv.x + wv.y * xv.y + wv.z * xv.z + wv.w * xv.w;
        }
        off[(size_t)r * C + t] = a;
    }
    if (t < 128) {
        const float4* w4 = (const float4*)(aw_w + (size_t)t * C);
        const float4* x4 = (const float4*)xs;
        float a = aw_b[t];
#pragma unroll 4
        for (int k = 0; k < C / 4; ++k) {
            float4 wv = w4[k], xv = x4[k];
            a += wv.x * xv.x + wv.y * xv.y + wv.z * xv.z + wv.w * xv.w;
        }
        logits[t] = a;
    }
    __syncthreads();
    if (t < 8) {  // one thread per head, softmax over 16
        float mx = -1e30f;
#pragma unroll
        for (int i = 0; i < 16; ++i) mx = fmaxf(mx, logits[t * 16 + i]);
        float e[16], s = 0.f;
#pragma unroll
        for (int i = 0; i < 16; ++i) { e[i] = expf(logits[t * 16 + i] - mx); s += e[i]; }
        float inv = 1.0f / s;
#pragma unroll
        for (int i = 0; i < 16; ++i) aw[(size_t)r * 128 + t * 16 + i] = e[i] * inv;
    }
}

// ---------------- deformable sampling ----------------
__global__ void k_sample(const float* __restrict__ trp, const float* __restrict__ off,
                         const float* __restrict__ aw, const float* __restrict__ value,
                         float* __restrict__ acc) {
    int r = blockIdx.x;              // token row = lq*B + b
    int b = r & 3;
    int t = threadIdx.x;
    int h = t >> 5, d = t & 31;
    const int Hs[4] = {100, 50, 25, 13};
    const int Ws[4] = {134, 67, 34, 17};
    const int Ss[4] = {0, 13400, 16750, 17600};
    const float* offr = off + (size_t)r * C;
    const float* awr = aw + (size_t)r * 128;
    const float* vb = value + ((size_t)b * NH + h) * (size_t)LVTOT * DH;
    float a = 0.f;
#pragma unroll
    for (int l = 0; l < 4; ++l) {
        float rx = trp[((size_t)r * NL + l) * 2 + 0];
        float ry = trp[((size_t)r * NL + l) * 2 + 1];
        int Hl = Hs[l], Wl = Ws[l], s = Ss[l];
        float fW = (float)Wl, fH = (float)Hl;
#pragma unroll
        for (int p = 0; p < 4; ++p) {
            float ox = offr[((h * NL + l) * NP + p) * 2 + 0];
            float oy = offr[((h * NL + l) * NP + p) * 2 + 1];
            float w = awr[h * 16 + l * 4 + p];
            float x = (rx + ox / fW) * fW - 0.5f;
            float y = (ry + oy / fH) * fH - 0.5f;
            float x0 = floorf(x), y0 = floorf(y);
            float sum = 0.f;
#pragma unroll
            for (int dy = 0; dy < 2; ++dy) {
#pragma unroll
                for (int dx = 0; dx < 2; ++dx) {
                    float xi = x0 + dx, yi = y0 + dy;
                    float wgt = (1.0f - fabsf(x - xi)) * (1.0f - fabsf(y - yi));
                    bool valid = (xi >= 0.f) && (xi < fW) && (yi >= 0.f) && (yi < fH);
                    int xic = min(max((int)xi, 0), Wl - 1);
                    int yic = min(max((int)yi, 0), Hl - 1);
                    float v = vb[((size_t)s + yic * Wl + xic) * DH + d];
                    sum += (valid ? wgt : 0.f) * v;
                }
            }
            a += w * sum;
        }
    }
    acc[(size_t)r * C + h * DH + d] = a;
}

// ---------------- fused single-row proj + residual + LN ----------------
__global__ void k_proj_res_ln(const float* __restrict__ inrow, const float* __restrict__ resid,
                              const float* __restrict__ W, const float* __restrict__ bias,
                              const float* __restrict__ g, const float* __restrict__ be,
                              float* __restrict__ out) {
    __shared__ float xs[C];
    __shared__ float pr[4];
    int r = blockIdx.x, t = threadIdx.x;
    xs[t] = inrow[(size_t)r * C + t];
    __syncthreads();
    const float4* w4 = (const float4*)(W + (size_t)t * C);
    const float4* x4 = (const float4*)xs;
    float a = bias[t];
#pragma unroll 4
    for (int k = 0; k < C / 4; ++k) {
        float4 wv = w4[k], xv = x4[k];
        a += wv.x * xv.x + wv.y * xv.y + wv.z * xv.z + wv.w * xv.w;
    }
    float v = a + resid[(size_t)r * C + t];
    float mean = block_sum256(v, pr) * (1.0f / C);
    float dv = v - mean;
    float var = block_sum256(dv * dv, pr) * (1.0f / C);
    out[(size_t)r * C + t] = dv * rsqrtf(var + 1e-5f) * g[t] + be[t];
}

// ---------------- residual + LN only ----------------
__global__ void k_res_ln(const float* __restrict__ Yin, const float* __restrict__ Xres,
                         const float* __restrict__ g, const float* __restrict__ be,
                         float* __restrict__ out) {
    __shared__ float pr[4];
    int r = blockIdx.x, t = threadIdx.x;
    float v = Yin[(size_t)r * C + t] + Xres[(size_t)r * C + t];
    float mean = block_sum256(v, pr) * (1.0f / C);
    float dv = v - mean;
    float var = block_sum256(dv * dv, pr) * (1.0f / C);
    out[(size_t)r * C + t] = dv * rsqrtf(var + 1e-5f) * g[t] + be[t];
}

// ---------------- flash attention: one block per (b,h, 32-query tile) ----------------
#define TQ 32
#define MK 64
#define KST 36            // padded K/V row stride (floats): conflict-free score reads
#define NCHUNK ((LQ + TQ - 1) / TQ)   // 29

__global__ void k_attn2(const float* __restrict__ Q, const float* __restrict__ K,
                        const float* __restrict__ V, float* __restrict__ O) {
    __shared__ float Ks[MK][KST];
    __shared__ float Vs[MK][KST];
    int blk = blockIdx.x;
    int bh = blk / NCHUNK;
    int q0 = (blk % NCHUNK) * TQ;
    int b = bh >> 3, h = bh & 7;
    int t = threadIdx.x;
    int q = t >> 3;          // 0..31 local query
    int kg = t & 7;          // 0..7 key group / d-group
    int d0 = kg * 4;

    const float* Qb = Q + (size_t)bh * LQ * DH;
    const float* Kb = K + (size_t)bh * LQ * DH;
    const float* Vb = V + (size_t)bh * LQ * DH;

    int qglob = q0 + q;
    const float* qrow = Qb + (size_t)min(qglob, LQ - 1) * DH;
    float4 qreg[8];
#pragma unroll
    for (int i = 0; i < 8; ++i) qreg[i] = *(const float4*)(qrow + i * 4);

    float m = -1e30f, l = 0.f;
    float acc[4] = {0.f, 0.f, 0.f, 0.f};

    for (int k0 = 0; k0 < LQ; k0 += MK) {
        __syncthreads();
#pragma unroll
        for (int rep = 0; rep < 2; ++rep) {
            int i = rep * 256 + t;
            int kk = i >> 3, dd = (i & 7) * 4;
            int kglob = k0 + kk;
            float4 kv, vv;
            if (kglob < LQ) {
                kv = *(const float4*)(Kb + (size_t)kglob * DH + dd);
                vv = *(const float4*)(Vb + (size_t)kglob * DH + dd);
            } else {
                kv = make_float4(0.f, 0.f, 0.f, 0.f);
                vv = make_float4(0.f, 0.f, 0.f, 0.f);
            }
            *(float4*)(&Ks[kk][dd]) = kv;
            *(float4*)(&Vs[kk][dd]) = vv;
        }
        __syncthreads();

        float sv[8];
        float cmax = -1e30f;
#pragma unroll
        for (int j = 0; j < 8; ++j) {
            int kk = kg + 8 * j;
            float s = 0.f;
#pragma unroll
            for (int i = 0; i < 8; ++i) {
                float4 kv = *(const float4*)(&Ks[kk][i * 4]);
                s += qreg[i].x * kv.x + qreg[i].y * kv.y + qreg[i].z * kv.z + qreg[i].w * kv.w;
            }
            bool valid = (k0 + kk) < LQ;
            s = valid ? s : -1e30f;
            sv[j] = s;
            cmax = fmaxf(cmax, s);
        }
#pragma unroll
        for (int o = 1; o < 8; o <<= 1) cmax = fmaxf(cmax, __shfl_xor(cmax, o, 8));
        float mnew = fmaxf(m, cmax);
        float scale = expf(m - mnew);
        float csum = 0.f;
#pragma unroll
        for (int j = 0; j < 8; ++j) {
            float e = (sv[j] > -1e29f) ? expf(sv[j] - mnew) : 0.f;
            sv[j] = e;
            csum += e;
        }
#pragma unroll
        for (int o = 1; o < 8; o <<= 1) csum += __shfl_xor(csum, o, 8);
        l = l * scale + csum;
        m = mnew;

        acc[0] *= scale; acc[1] *= scale; acc[2] *= scale; acc[3] *= scale;
#pragma unroll
        for (int j = 0; j < 8; ++j) {
#pragma unroll
            for (int i = 0; i < 8; ++i) {
                int kk = j * 8 + i;
                float p = __shfl(sv[j], i, 8);
                float4 vv = *(const float4*)(&Vs[kk][d0]);
                acc[0] += p * vv.x; acc[1] += p * vv.y; acc[2] += p * vv.z; acc[3] += p * vv.w;
            }
        }
    }

    if (qglob < LQ) {
        float inv = 1.0f / l;
        int lq = qglob;
        float* o = O + ((size_t)(lq * BQ + b)) * C + h * DH + d0;
        o[0] = acc[0] * inv; o[1] = acc[1] * inv; o[2] = acc[2] * inv; o[3] = acc[3] * inv;
    }
}

// ---------------- launch ----------------
extern "C" void kernel_launch(void* const* d_in, const int* in_sizes, int n_in,
                              void* d_out, int out_size, void* d_ws, size_t ws_size,
                              hipStream_t stream) {
    const float* tgt      = (const float*)d_in[0];
    const float* trp      = (const float*)d_in[1];
    const float* memory   = (const float*)d_in[2];
    const float* vproj_w  = (const float*)d_in[5];  const float* vproj_b  = (const float*)d_in[6];
    const float* off_w    = (const float*)d_in[7];  const float* off_b    = (const float*)d_in[8];
    const float* aw_w     = (const float*)d_in[9];  const float* aw_b     = (const float*)d_in[10];
    const float* oproj_w  = (const float*)d_in[11]; const float* oproj_b  = (const float*)d_in[12];
    const float* ln1_g    = (const float*)d_in[13]; const float* ln1_b    = (const float*)d_in[14];
    const float* sa_in_w  = (const float*)d_in[15]; const float* sa_in_b  = (const float*)d_in[16];
    const float* sa_out_w = (const float*)d_in[17]; const float* sa_out_b = (const float*)d_in[18];
    const float* ln2_g    = (const float*)d_in[19]; const float* ln2_b    = (const float*)d_in[20];
    const float* l1_w     = (const float*)d_in[21]; const float* l1_b     = (const float*)d_in[22];
    const float* l2_w     = (const float*)d_in[23]; const float* l2_b     = (const float*)d_in[24];
    const float* ln3_g    = (const float*)d_in[25]; const float* ln3_b    = (const float*)d_in[26];
    const float* sa3_in_w = (const float*)d_in[27]; const float* sa3_in_b = (const float*)d_in[28];
    const float* sa3_out_w= (const float*)d_in[29]; const float* sa3_out_b= (const float*)d_in[30];
    const float* ln5_g    = (const float*)d_in[31]; const float* ln5_b    = (const float*)d_in[32];
    const float* l31_w    = (const float*)d_in[33]; const float* l31_b    = (const float*)d_in[34];
    const float* l32_w    = (const float*)d_in[35]; const float* l32_b    = (const float*)d_in[36];
    const float* ln33_g   = (const float*)d_in[37]; const float* ln33_b   = (const float*)d_in[38];

    float* ws = (float*)d_ws;
    float* X     = ws;                       // 921,600  (current residual stream, token layout)
    float* value = ws + 921600;              // 18,248,704  [B,H,LV,32]
    float* off   = value + 18248704;         // 921,600
    float* aw    = off + 921600;             // 460,800
    float* acc   = aw + 460800;              // 921,600
    // value region reused after cross-attn:
    float* QKV = value;                      // 2,764,800 (Q|K|V each 921,600)
    float* O   = value + 2764800;            // 921,600
    float* H1  = value + 3686400;            // 7,372,800
    float* Y   = value + 11059200;           // 921,600

    const int NVROWS = BQ * LVTOT;           // 71,284
    dim3 blk(256);

    // ---- ca: MSDeformAttn ----
    k_mgemm<256, MODE_VALUE><<<dim3((NVROWS + 127) / 128, 4), blk, 0, stream>>>(memory, vproj_w, vproj_b, value, NVROWS);
    k_off_aw<<<NTOK, blk, 0, stream>>>(tgt, off_w, off_b, aw_w, aw_b, off, aw);
    k_sample<<<NTOK, blk, 0, stream>>>(trp, off, aw, value, acc);
    k_proj_res_ln<<<NTOK, blk, 0, stream>>>(acc, tgt, oproj_w, oproj_b, ln1_g, ln1_b, X);

    // ---- sa ----
    k_mgemm<256, MODE_QKV><<<dim3((NTOK + 127) / 128, 12), blk, 0, stream>>>(X, sa_in_w, sa_in_b, QKV, NTOK);
    k_attn2<<<BQ * NH * NCHUNK, blk, 0, stream>>>(QKV, QKV + 921600, QKV + 1843200, O);
    k_proj_res_ln<<<NTOK, blk, 0, stream>>>(O, X, sa_out_w, sa_out_b, ln2_g, ln2_b, X);

    // ---- ffn ----
    k_mgemm<256, MODE_RELU><<<dim3((NTOK + 127) / 128, 32), blk, 0, stream>>>(X, l1_w, l1_b, H1, NTOK);
    k_mgemm<2048, MODE_NORMAL><<<dim3((NTOK + 127) / 128, 4), blk, 0, stream>>>(H1, l2_w, l2_b, Y, NTOK);
    k_res_ln<<<NTOK, blk, 0, stream>>>(Y, X, ln3_g, ln3_b, X);

    // ---- sa3 ----
    k_mgemm<256, MODE_QKV><<<dim3((NTOK + 127) / 128, 12), blk, 0, stream>>>(X, sa3_in_w, sa3_in_b, QKV, NTOK);
    k_attn2<<<BQ * NH * NCHUNK, blk, 0, stream>>>(QKV, QKV + 921600, QKV + 1843200, O);
    k_proj_res_ln<<<NTOK, blk, 0, stream>>>(O, X, sa3_out_w, sa3_out_b, ln5_g, ln5_b, X);

    // ---- ffn3 ----
    k_mgemm<256, MODE_RELU><<<dim3((NTOK + 127) / 128, 32), blk, 0, stream>>>(X, l31_w, l31_b, H1, NTOK);
    k_mgemm<2048, MODE_NORMAL><<<dim3((NTOK + 127) / 128, 4), blk, 0, stream>>>(H1, l32_w, l32_b, Y, NTOK);
    k_res_ln<<<NTOK, blk, 0, stream>>>(Y, X, ln33_g, ln33_b, (float*)d_out);
}

// Round 5
// 831.353 us; speedup vs baseline: 3.6048x; 1.4417x over previous
//
#include <hip/hip_runtime.h>
#include <math.h>

#define C 256
#define DH 32
#define NH 8
#define NL 4
#define NP 4
#define BQ 4
#define LQ 900
#define LVTOT 17821
#define DFFN 2048
#define NTOK (BQ*LQ)          // 3600 token rows, token index t = lq*B + b

typedef __attribute__((ext_vector_type(8))) short bf8_t;    // 8 bf16 (4 VGPRs)
typedef __attribute__((ext_vector_type(4))) float f4_t;     // MFMA acc
typedef __attribute__((ext_vector_type(8))) unsigned short us8_t;

// ---------------- block reductions (256 threads, wave64) ----------------
__device__ __forceinline__ float block_sum256(float v, float* pr) {
    int t = threadIdx.x, lane = t & 63, wv = t >> 6;
#pragma unroll
    for (int o = 32; o > 0; o >>= 1) v += __shfl_down(v, o, 64);
    if (lane == 0) pr[wv] = v;
    __syncthreads();
    float r = pr[0] + pr[1] + pr[2] + pr[3];
    __syncthreads();
    return r;
}

__device__ __forceinline__ unsigned short f2bf(float f) {
    unsigned int u = __float_as_uint(f);
    u += 0x7fffu + ((u >> 16) & 1u);   // round-to-nearest-even
    return (unsigned short)(u >> 16);
}

// ---------------- bf16 MFMA GEMM: Y = act(A @ W^T + b) ----------------
// A: [nrows][KS] fp32 row-major (process K of it); W: [OC][KS] fp32 row-major.
// Block tile 128(M) x 64(N), 4 waves in 2x2, K-step 32. fp32 staged -> bf16 LDS.
enum { MODE_NORMAL = 0, MODE_RELU = 1, MODE_VALUE = 2, MODE_QKV = 3 };

#define LDP 72   // LDS row stride in bf16 elems (144 B = 9*16B: aligned b128, conflict-free)

template<int K, int KS, int MODE>
__global__ void k_mgemm(const float* __restrict__ A, const float* __restrict__ W,
                        const float* __restrict__ bias, float* __restrict__ Y, int nrows) {
    __shared__ unsigned short Ash[128 * LDP];
    __shared__ unsigned short Bsh[64 * LDP];
    int t = threadIdx.x;
    int lane = t & 63, w = t >> 6;
    int wm = w & 1, wn = w >> 1;
    int r0 = blockIdx.x * 128;
    int c0 = blockIdx.y * 64;

    f4_t acc[4][2];
#pragma unroll
    for (int mt = 0; mt < 4; ++mt)
#pragma unroll
        for (int nt = 0; nt < 2; ++nt) acc[mt][nt] = (f4_t)0.f;

    // staging geometry
    int arow = t >> 1;                 // 0..127
    int akoff = (t & 1) * 16;          // 0 or 16
    int asrc = min(r0 + arow, nrows - 1);
    const float* aptr = A + (size_t)asrc * KS + akoff;
    unsigned short* adst = &Ash[arow * LDP + akoff];

    int brow = t >> 2;                 // 0..63
    int bkoff = (t & 3) * 8;
    const float* bptr = W + (size_t)(c0 + brow) * KS + bkoff;
    unsigned short* bdst = &Bsh[brow * LDP + bkoff];

    int lr = lane & 15, kg = lane >> 4;

    for (int k0 = 0; k0 < K; k0 += 32) {
        __syncthreads();
        // stage A: 16 floats -> 16 bf16 (two 16B LDS writes)
        {
            float4 av0 = *(const float4*)(aptr + k0);
            float4 av1 = *(const float4*)(aptr + k0 + 4);
            float4 av2 = *(const float4*)(aptr + k0 + 8);
            float4 av3 = *(const float4*)(aptr + k0 + 12);
            us8_t u0, u1;
            u0[0]=f2bf(av0.x); u0[1]=f2bf(av0.y); u0[2]=f2bf(av0.z); u0[3]=f2bf(av0.w);
            u0[4]=f2bf(av1.x); u0[5]=f2bf(av1.y); u0[6]=f2bf(av1.z); u0[7]=f2bf(av1.w);
            u1[0]=f2bf(av2.x); u1[1]=f2bf(av2.y); u1[2]=f2bf(av2.z); u1[3]=f2bf(av2.w);
            u1[4]=f2bf(av3.x); u1[5]=f2bf(av3.y); u1[6]=f2bf(av3.z); u1[7]=f2bf(av3.w);
            *(us8_t*)(adst) = u0;
            *(us8_t*)(adst + 8) = u1;
        }
        // stage B: 8 floats -> 8 bf16 (one 16B LDS write)
        {
            float4 bv0 = *(const float4*)(bptr + k0);
            float4 bv1 = *(const float4*)(bptr + k0 + 4);
            us8_t u;
            u[0]=f2bf(bv0.x); u[1]=f2bf(bv0.y); u[2]=f2bf(bv0.z); u[3]=f2bf(bv0.w);
            u[4]=f2bf(bv1.x); u[5]=f2bf(bv1.y); u[6]=f2bf(bv1.z); u[7]=f2bf(bv1.w);
            *(us8_t*)(bdst) = u;
        }
        __syncthreads();

        bf8_t afr[4], bfr[2];
#pragma unroll
        for (int mt = 0; mt < 4; ++mt)
            afr[mt] = *(const bf8_t*)&Ash[(wm * 64 + mt * 16 + lr) * LDP + kg * 8];
#pragma unroll
        for (int nt = 0; nt < 2; ++nt)
            bfr[nt] = *(const bf8_t*)&Bsh[(wn * 32 + nt * 16 + lr) * LDP + kg * 8];
#pragma unroll
        for (int mt = 0; mt < 4; ++mt)
#pragma unroll
            for (int nt = 0; nt < 2; ++nt)
                acc[mt][nt] = __builtin_amdgcn_mfma_f32_16x16x32_bf16(afr[mt], bfr[nt], acc[mt][nt], 0, 0, 0);
    }

    // epilogue
#pragma unroll
    for (int mt = 0; mt < 4; ++mt) {
#pragma unroll
        for (int nt = 0; nt < 2; ++nt) {
            int col = c0 + wn * 32 + nt * 16 + lr;
            float b0 = bias ? bias[col] : 0.f;
#pragma unroll
            for (int rr = 0; rr < 4; ++rr) {
                int row = r0 + wm * 64 + mt * 16 + kg * 4 + rr;
                if (row >= nrows) continue;
                float v = acc[mt][nt][rr] + b0;
                if (MODE == MODE_NORMAL) {
                    Y[(size_t)row * gridDim.y * 64 + col] = v;
                } else if (MODE == MODE_RELU) {
                    Y[(size_t)row * gridDim.y * 64 + col] = fmaxf(v, 0.f);
                } else if (MODE == MODE_VALUE) {
                    int lv = row >> 2, b = row & 3;      // memory row = lv*B + b
                    int h = col >> 5, d = col & 31;
                    Y[(((size_t)b * NH + h) * LVTOT + lv) * DH + d] = v;
                } else { // MODE_QKV
                    int lq = row >> 2, b = row & 3;      // token row = lq*B + b
                    int part = col >> 8, cc = col & 255;
                    int h = cc >> 5, d = cc & 31;
                    if (part == 0) v *= 0.17677669529663687f;  // 1/sqrt(32)
                    Y[(size_t)part * (BQ * NH * LQ * DH) + (((size_t)b * NH + h) * LQ + lq) * DH + d] = v;
                }
            }
        }
    }
}

// ---------------- deformable sampling (aw softmax folded in) ----------------
__global__ void k_sample(const float* __restrict__ trp, const float* __restrict__ off,
                         const float* __restrict__ awl, const float* __restrict__ value,
                         float* __restrict__ acc) {
    int r = blockIdx.x;              // token row = lq*B + b
    int b = r & 3;
    int t = threadIdx.x;
    int h = t >> 5, d = t & 31;
    const int Hs[4] = {100, 50, 25, 13};
    const int Ws[4] = {134, 67, 34, 17};
    const int Ss[4] = {0, 13400, 16750, 17600};
    const float* offr = off + (size_t)r * C;
    const float* vb = value + ((size_t)b * NH + h) * (size_t)LVTOT * DH;

    // per-head softmax over the 16 logits (redundant across the 32 lanes of a head)
    const float* lg = awl + (size_t)r * 128 + h * 16;
    float lv[16];
#pragma unroll
    for (int i = 0; i < 4; ++i) {
        float4 q = *(const float4*)(lg + i * 4);
        lv[i*4+0] = q.x; lv[i*4+1] = q.y; lv[i*4+2] = q.z; lv[i*4+3] = q.w;
    }
    float mx = -1e30f;
#pragma unroll
    for (int i = 0; i < 16; ++i) mx = fmaxf(mx, lv[i]);
    float ssum = 0.f;
#pragma unroll
    for (int i = 0; i < 16; ++i) { lv[i] = expf(lv[i] - mx); ssum += lv[i]; }
    float sinv = 1.0f / ssum;

    float a = 0.f;
#pragma unroll
    for (int l = 0; l < 4; ++l) {
        float rx = trp[((size_t)r * NL + l) * 2 + 0];
        float ry = trp[((size_t)r * NL + l) * 2 + 1];
        int Hl = Hs[l], Wl = Ws[l], s = Ss[l];
        float fW = (float)Wl, fH = (float)Hl;
#pragma unroll
        for (int p = 0; p < 4; ++p) {
            float ox = offr[((h * NL + l) * NP + p) * 2 + 0];
            float oy = offr[((h * NL + l) * NP + p) * 2 + 1];
            float w = lv[l * 4 + p] * sinv;
            float x = (rx + ox / fW) * fW - 0.5f;
            float y = (ry + oy / fH) * fH - 0.5f;
            float x0 = floorf(x), y0 = floorf(y);
            float sum = 0.f;
#pragma unroll
            for (int dy = 0; dy < 2; ++dy) {
#pragma unroll
                for (int dx = 0; dx < 2; ++dx) {
                    float xi = x0 + dx, yi = y0 + dy;
                    float wgt = (1.0f - fabsf(x - xi)) * (1.0f - fabsf(y - yi));
                    bool valid = (xi >= 0.f) && (xi < fW) && (yi >= 0.f) && (yi < fH);
                    int xic = min(max((int)xi, 0), Wl - 1);
                    int yic = min(max((int)yi, 0), Hl - 1);
                    float v = vb[((size_t)s + yic * Wl + xic) * DH + d];
                    sum += (valid ? wgt : 0.f) * v;
                }
            }
            a += w * sum;
        }
    }
    acc[(size_t)r * C + h * DH + d] = a;
}

// ---------------- residual + LN ----------------
__global__ void k_res_ln(const float* __restrict__ Yin, const float* __restrict__ Xres,
                         const float* __restrict__ g, const float* __restrict__ be,
                         float* __restrict__ out) {
    __shared__ float pr[4];
    int r = blockIdx.x, t = threadIdx.x;
    float v = Yin[(size_t)r * C + t] + Xres[(size_t)r * C + t];
    float mean = block_sum256(v, pr) * (1.0f / C);
    float dv = v - mean;
    float var = block_sum256(dv * dv, pr) * (1.0f / C);
    out[(size_t)r * C + t] = dv * rsqrtf(var + 1e-5f) * g[t] + be[t];
}

// ---------------- split-K sum + residual + LN ----------------
__global__ void k_res_ln2(const float* __restrict__ Y0, const float* __restrict__ Y1,
                          const float* __restrict__ Xres,
                          const float* __restrict__ g, const float* __restrict__ be,
                          float* __restrict__ out) {
    __shared__ float pr[4];
    int r = blockIdx.x, t = threadIdx.x;
    float v = Y0[(size_t)r * C + t] + Y1[(size_t)r * C + t] + Xres[(size_t)r * C + t];
    float mean = block_sum256(v, pr) * (1.0f / C);
    float dv = v - mean;
    float var = block_sum256(dv * dv, pr) * (1.0f / C);
    out[(size_t)r * C + t] = dv * rsqrtf(var + 1e-5f) * g[t] + be[t];
}

// ---------------- flash attention: chunk-major blocks for XCD L2 locality ----------------
#define TQ 32
#define MK 64
#define KST 36            // padded K/V row stride (floats): conflict-free score reads
#define NCHUNK ((LQ + TQ - 1) / TQ)   // 29; grid = NCHUNK*32, bh = blk&31 -> XCD = bh%8

__global__ void k_attn2(const float* __restrict__ Q, const float* __restrict__ K,
                        const float* __restrict__ V, float* __restrict__ O) {
    __shared__ float Ks[MK][KST];
    __shared__ float Vs[MK][KST];
    int blk = blockIdx.x;
    int bh = blk & 31;               // all chunks of a bh share an XCD (L2 locality)
    int q0 = (blk >> 5) * TQ;
    int b = bh >> 3, h = bh & 7;
    int t = threadIdx.x;
    int q = t >> 3;          // 0..31 local query
    int kg = t & 7;          // 0..7 key group / d-group
    int d0 = kg * 4;

    const float* Qb = Q + (size_t)bh * LQ * DH;
    const float* Kb = K + (size_t)bh * LQ * DH;
    const float* Vb = V + (size_t)bh * LQ * DH;

    int qglob = q0 + q;
    const float* qrow = Qb + (size_t)min(qglob, LQ - 1) * DH;
    float4 qreg[8];
#pragma unroll
    for (int i = 0; i < 8; ++i) qreg[i] = *(const float4*)(qrow + i * 4);

    float m = -1e30f, l = 0.f;
    float acc[4] = {0.f, 0.f, 0.f, 0.f};

    for (int k0 = 0; k0 < LQ; k0 += MK) {
        __syncthreads();
#pragma unroll
        for (int rep = 0; rep < 2; ++rep) {
            int i = rep * 256 + t;
            int kk = i >> 3, dd = (i & 7) * 4;
            int kglob = k0 + kk;
            float4 kv, vv;
            if (kglob < LQ) {
                kv = *(const float4*)(Kb + (size_t)kglob * DH + dd);
                vv = *(const float4*)(Vb + (size_t)kglob * DH + dd);
            } else {
                kv = make_float4(0.f, 0.f, 0.f, 0.f);
                vv = make_float4(0.f, 0.f, 0.f, 0.f);
            }
            *(float4*)(&Ks[kk][dd]) = kv;
            *(float4*)(&Vs[kk][dd]) = vv;
        }
        __syncthreads();

        float sv[8];
        float cmax = -1e30f;
#pragma unroll
        for (int j = 0; j < 8; ++j) {
            int kk = kg + 8 * j;
            float s = 0.f;
#pragma unroll
            for (int i = 0; i < 8; ++i) {
                float4 kv = *(const float4*)(&Ks[kk][i * 4]);
                s += qreg[i].x * kv.x + qreg[i].y * kv.y + qreg[i].z * kv.z + qreg[i].w * kv.w;
            }
            bool valid = (k0 + kk) < LQ;
            s = valid ? s : -1e30f;
            sv[j] = s;
            cmax = fmaxf(cmax, s);
        }
#pragma unroll
        for (int o = 1; o < 8; o <<= 1) cmax = fmaxf(cmax, __shfl_xor(cmax, o, 8));
        float mnew = fmaxf(m, cmax);
        float scale = expf(m - mnew);
        float csum = 0.f;
#pragma unroll
        for (int j = 0; j < 8; ++j) {
            float e = (sv[j] > -1e29f) ? expf(sv[j] - mnew) : 0.f;
            sv[j] = e;
            csum += e;
        }
#pragma unroll
        for (int o = 1; o < 8; o <<= 1) csum += __shfl_xor(csum, o, 8);
        l = l * scale + csum;
        m = mnew;

        acc[0] *= scale; acc[1] *= scale; acc[2] *= scale; acc[3] *= scale;
#pragma unroll
        for (int j = 0; j < 8; ++j) {
#pragma unroll
            for (int i = 0; i < 8; ++i) {
                int kk = j * 8 + i;
                float p = __shfl(sv[j], i, 8);
                float4 vv = *(const float4*)(&Vs[kk][d0]);
                acc[0] += p * vv.x; acc[1] += p * vv.y; acc[2] += p * vv.z; acc[3] += p * vv.w;
            }
        }
    }

    if (qglob < LQ) {
        float inv = 1.0f / l;
        int lq = qglob;
        float* o = O + ((size_t)(lq * BQ + b)) * C + h * DH + d0;
        o[0] = acc[0] * inv; o[1] = acc[1] * inv; o[2] = acc[2] * inv; o[3] = acc[3] * inv;
    }
}

// ---------------- launch ----------------
extern "C" void kernel_launch(void* const* d_in, const int* in_sizes, int n_in,
                              void* d_out, int out_size, void* d_ws, size_t ws_size,
                              hipStream_t stream) {
    const float* tgt      = (const float*)d_in[0];
    const float* trp      = (const float*)d_in[1];
    const float* memory   = (const float*)d_in[2];
    const float* vproj_w  = (const float*)d_in[5];  const float* vproj_b  = (const float*)d_in[6];
    const float* off_w    = (const float*)d_in[7];  const float* off_b    = (const float*)d_in[8];
    const float* aw_w     = (const float*)d_in[9];  const float* aw_b     = (const float*)d_in[10];
    const float* oproj_w  = (const float*)d_in[11]; const float* oproj_b  = (const float*)d_in[12];
    const float* ln1_g    = (const float*)d_in[13]; const float* ln1_b    = (const float*)d_in[14];
    const float* sa_in_w  = (const float*)d_in[15]; const float* sa_in_b  = (const float*)d_in[16];
    const float* sa_out_w = (const float*)d_in[17]; const float* sa_out_b = (const float*)d_in[18];
    const float* ln2_g    = (const float*)d_in[19]; const float* ln2_b    = (const float*)d_in[20];
    const float* l1_w     = (const float*)d_in[21]; const float* l1_b     = (const float*)d_in[22];
    const float* l2_w     = (const float*)d_in[23]; const float* l2_b     = (const float*)d_in[24];
    const float* ln3_g    = (const float*)d_in[25]; const float* ln3_b    = (const float*)d_in[26];
    const float* sa3_in_w = (const float*)d_in[27]; const float* sa3_in_b = (const float*)d_in[28];
    const float* sa3_out_w= (const float*)d_in[29]; const float* sa3_out_b= (const float*)d_in[30];
    const float* ln5_g    = (const float*)d_in[31]; const float* ln5_b    = (const float*)d_in[32];
    const float* l31_w    = (const float*)d_in[33]; const float* l31_b    = (const float*)d_in[34];
    const float* l32_w    = (const float*)d_in[35]; const float* l32_b    = (const float*)d_in[36];
    const float* ln33_g   = (const float*)d_in[37]; const float* ln33_b   = (const float*)d_in[38];

    float* ws = (float*)d_ws;
    float* X     = ws;                       // 921,600  (current residual stream, token layout)
    float* value = ws + 921600;              // 18,248,704  [B,H,LV,32]
    float* off   = value + 18248704;         // 921,600
    float* aw    = off + 921600;             // 460,800 (logits)
    float* acc   = aw + 460800;              // 921,600
    // value region reused after sampling is done / between phases:
    float* QKV = value;                      // 2,764,800 (Q|K|V each 921,600)
    float* O   = value + 2764800;            // 921,600
    float* H1  = value + 3686400;            // 7,372,800 (also proj scratch T1)
    float* Y   = value + 11059200;           // 921,600
    float* Y2  = value + 11980800;           // 921,600 (split-K partial)
    float* T1  = H1;                         // proj output scratch (free outside FFN)

    const int NVROWS = BQ * LVTOT;           // 71,284
    dim3 blk(256);
    dim3 gTok(29, 4);                        // 3600-row x 256-col GEMM grid

    // ---- ca: MSDeformAttn ----
    k_mgemm<256, 256, MODE_VALUE><<<dim3((NVROWS + 127) / 128, 4), blk, 0, stream>>>(memory, vproj_w, vproj_b, value, NVROWS);
    k_mgemm<256, 256, MODE_NORMAL><<<gTok, blk, 0, stream>>>(tgt, off_w, off_b, off, NTOK);
    k_mgemm<256, 256, MODE_NORMAL><<<dim3(29, 2), blk, 0, stream>>>(tgt, aw_w, aw_b, aw, NTOK);
    k_sample<<<NTOK, blk, 0, stream>>>(trp, off, aw, value, acc);
    k_mgemm<256, 256, MODE_NORMAL><<<gTok, blk, 0, stream>>>(acc, oproj_w, oproj_b, T1, NTOK);
    k_res_ln<<<NTOK, blk, 0, stream>>>(T1, tgt, ln1_g, ln1_b, X);

    // ---- sa ----
    k_mgemm<256, 256, MODE_QKV><<<dim3(29, 12), blk, 0, stream>>>(X, sa_in_w, sa_in_b, QKV, NTOK);
    k_attn2<<<32 * NCHUNK, blk, 0, stream>>>(QKV, QKV + 921600, QKV + 1843200, O);
    k_mgemm<256, 256, MODE_NORMAL><<<gTok, blk, 0, stream>>>(O, sa_out_w, sa_out_b, T1, NTOK);
    k_res_ln<<<NTOK, blk, 0, stream>>>(T1, X, ln2_g, ln2_b, X);

    // ---- ffn ----
    k_mgemm<256, 256, MODE_RELU><<<dim3(29, 32), blk, 0, stream>>>(X, l1_w, l1_b, H1, NTOK);
    k_mgemm<1024, 2048, MODE_NORMAL><<<gTok, blk, 0, stream>>>(H1, l2_w, l2_b, Y, NTOK);
    k_mgemm<1024, 2048, MODE_NORMAL><<<gTok, blk, 0, stream>>>(H1 + 1024, l2_w + 1024, (const float*)nullptr, Y2, NTOK);
    k_res_ln2<<<NTOK, blk, 0, stream>>>(Y, Y2, X, ln3_g, ln3_b, X);

    // ---- sa3 ----
    k_mgemm<256, 256, MODE_QKV><<<dim3(29, 12), blk, 0, stream>>>(X, sa3_in_w, sa3_in_b, QKV, NTOK);
    k_attn2<<<32 * NCHUNK, blk, 0, stream>>>(QKV, QKV + 921600, QKV + 1843200, O);
    k_mgemm<256, 256, MODE_NORMAL><<<gTok, blk, 0, stream>>>(O, sa3_out_w, sa3_out_b, T1, NTOK);
    k_res_ln<<<NTOK, blk, 0, stream>>>(T1, X, ln5_g, ln5_b, X);

    // ---- ffn3 ----
    k_mgemm<256, 256, MODE_RELU><<<dim3(29, 32), blk, 0, stream>>>(X, l31_w, l31_b, H1, NTOK);
    k_mgemm<1024, 2048, MODE_NORMAL><<<gTok, blk, 0, stream>>>(H1, l32_w, l32_b, Y, NTOK);
    k_mgemm<1024, 2048, MODE_NORMAL><<<gTok, blk, 0, stream>>>(H1 + 1024, l32_w + 1024, (const float*)nullptr, Y2, NTOK);
    k_res_ln2<<<NTOK, blk, 0, stream>>>(Y, Y2, X, ln33_g, ln33_b, (float*)d_out);
}

// Round 6
// 588.238 us; speedup vs baseline: 5.0946x; 1.4133x over previous
//
#include <hip/hip_runtime.h>
#include <math.h>

#define C 256
#define DH 32
#define NH 8
#define NL 4
#define NP 4
#define BQ 4
#define LQ 900
#define LVTOT 17821
#define DFFN 2048
#define NTOK (BQ*LQ)          // 3600 token rows, token index t = lq*B + b

typedef __attribute__((ext_vector_type(8))) short bf8_t;    // 8 bf16 (4 VGPRs)
typedef __attribute__((ext_vector_type(4))) float f4_t;     // MFMA acc
typedef __attribute__((ext_vector_type(8))) unsigned short us8_t;
typedef __attribute__((ext_vector_type(4))) unsigned short us4_t;

// ---------------- block reductions (256 threads, wave64) ----------------
__device__ __forceinline__ float block_sum256(float v, float* pr) {
    int t = threadIdx.x, lane = t & 63, wv = t >> 6;
#pragma unroll
    for (int o = 32; o > 0; o >>= 1) v += __shfl_down(v, o, 64);
    if (lane == 0) pr[wv] = v;
    __syncthreads();
    float r = pr[0] + pr[1] + pr[2] + pr[3];
    __syncthreads();
    return r;
}

__device__ __forceinline__ unsigned short f2bf(float f) {
    unsigned int u = __float_as_uint(f);
    u += 0x7fffu + ((u >> 16) & 1u);   // round-to-nearest-even
    return (unsigned short)(u >> 16);
}

// ---------------- bf16 MFMA GEMM: Y = act(A @ W^T + b) ----------------
enum { MODE_NORMAL = 0, MODE_RELU = 1, MODE_VALUE = 2, MODE_QKV = 3 };

#define LDP 72   // LDS row stride in bf16 elems (144 B = 9*16B: aligned b128)

template<int K, int KS, int MODE>
__global__ void k_mgemm(const float* __restrict__ A, const float* __restrict__ W,
                        const float* __restrict__ bias, float* __restrict__ Y, int nrows) {
    __shared__ unsigned short Ash[128 * LDP];
    __shared__ unsigned short Bsh[64 * LDP];
    int t = threadIdx.x;
    int lane = t & 63, w = t >> 6;
    int wm = w & 1, wn = w >> 1;
    int r0 = blockIdx.x * 128;
    int c0 = blockIdx.y * 64;

    f4_t acc[4][2];
#pragma unroll
    for (int mt = 0; mt < 4; ++mt)
#pragma unroll
        for (int nt = 0; nt < 2; ++nt) acc[mt][nt] = (f4_t)0.f;

    int arow = t >> 1;
    int akoff = (t & 1) * 16;
    int asrc = min(r0 + arow, nrows - 1);
    const float* aptr = A + (size_t)asrc * KS + akoff;
    unsigned short* adst = &Ash[arow * LDP + akoff];

    int brow = t >> 2;
    int bkoff = (t & 3) * 8;
    const float* bptr = W + (size_t)(c0 + brow) * KS + bkoff;
    unsigned short* bdst = &Bsh[brow * LDP + bkoff];

    int lr = lane & 15, kg = lane >> 4;

    for (int k0 = 0; k0 < K; k0 += 32) {
        __syncthreads();
        {
            float4 av0 = *(const float4*)(aptr + k0);
            float4 av1 = *(const float4*)(aptr + k0 + 4);
            float4 av2 = *(const float4*)(aptr + k0 + 8);
            float4 av3 = *(const float4*)(aptr + k0 + 12);
            us8_t u0, u1;
            u0[0]=f2bf(av0.x); u0[1]=f2bf(av0.y); u0[2]=f2bf(av0.z); u0[3]=f2bf(av0.w);
            u0[4]=f2bf(av1.x); u0[5]=f2bf(av1.y); u0[6]=f2bf(av1.z); u0[7]=f2bf(av1.w);
            u1[0]=f2bf(av2.x); u1[1]=f2bf(av2.y); u1[2]=f2bf(av2.z); u1[3]=f2bf(av2.w);
            u1[4]=f2bf(av3.x); u1[5]=f2bf(av3.y); u1[6]=f2bf(av3.z); u1[7]=f2bf(av3.w);
            *(us8_t*)(adst) = u0;
            *(us8_t*)(adst + 8) = u1;
        }
        {
            float4 bv0 = *(const float4*)(bptr + k0);
            float4 bv1 = *(const float4*)(bptr + k0 + 4);
            us8_t u;
            u[0]=f2bf(bv0.x); u[1]=f2bf(bv0.y); u[2]=f2bf(bv0.z); u[3]=f2bf(bv0.w);
            u[4]=f2bf(bv1.x); u[5]=f2bf(bv1.y); u[6]=f2bf(bv1.z); u[7]=f2bf(bv1.w);
            *(us8_t*)(bdst) = u;
        }
        __syncthreads();

        bf8_t afr[4], bfr[2];
#pragma unroll
        for (int mt = 0; mt < 4; ++mt)
            afr[mt] = *(const bf8_t*)&Ash[(wm * 64 + mt * 16 + lr) * LDP + kg * 8];
#pragma unroll
        for (int nt = 0; nt < 2; ++nt)
            bfr[nt] = *(const bf8_t*)&Bsh[(wn * 32 + nt * 16 + lr) * LDP + kg * 8];
#pragma unroll
        for (int mt = 0; mt < 4; ++mt)
#pragma unroll
            for (int nt = 0; nt < 2; ++nt)
                acc[mt][nt] = __builtin_amdgcn_mfma_f32_16x16x32_bf16(afr[mt], bfr[nt], acc[mt][nt], 0, 0, 0);
    }

#pragma unroll
    for (int mt = 0; mt < 4; ++mt) {
#pragma unroll
        for (int nt = 0; nt < 2; ++nt) {
            int col = c0 + wn * 32 + nt * 16 + lr;
            float b0 = bias ? bias[col] : 0.f;
#pragma unroll
            for (int rr = 0; rr < 4; ++rr) {
                int row = r0 + wm * 64 + mt * 16 + kg * 4 + rr;
                if (row >= nrows) continue;
                float v = acc[mt][nt][rr] + b0;
                if (MODE == MODE_NORMAL) {
                    Y[(size_t)row * gridDim.y * 64 + col] = v;
                } else if (MODE == MODE_RELU) {
                    Y[(size_t)row * gridDim.y * 64 + col] = fmaxf(v, 0.f);
                } else if (MODE == MODE_VALUE) {
                    int lv = row >> 2, b = row & 3;
                    int h = col >> 5, d = col & 31;
                    Y[(((size_t)b * NH + h) * LVTOT + lv) * DH + d] = v;
                } else { // MODE_QKV
                    int lq = row >> 2, b = row & 3;
                    int part = col >> 8, cc = col & 255;
                    int h = cc >> 5, d = cc & 31;
                    if (part == 0) v *= 0.17677669529663687f;  // 1/sqrt(32)
                    Y[(size_t)part * (BQ * NH * LQ * DH) + (((size_t)b * NH + h) * LQ + lq) * DH + d] = v;
                }
            }
        }
    }
}

// ---------------- deformable sampling (aw softmax folded in) ----------------
__global__ void k_sample(const float* __restrict__ trp, const float* __restrict__ off,
                         const float* __restrict__ awl, const float* __restrict__ value,
                         float* __restrict__ acc) {
    int r = blockIdx.x;
    int b = r & 3;
    int t = threadIdx.x;
    int h = t >> 5, d = t & 31;
    const int Hs[4] = {100, 50, 25, 13};
    const int Ws[4] = {134, 67, 34, 17};
    const int Ss[4] = {0, 13400, 16750, 17600};
    const float* offr = off + (size_t)r * C;
    const float* vb = value + ((size_t)b * NH + h) * (size_t)LVTOT * DH;

    const float* lg = awl + (size_t)r * 128 + h * 16;
    float lv[16];
#pragma unroll
    for (int i = 0; i < 4; ++i) {
        float4 q = *(const float4*)(lg + i * 4);
        lv[i*4+0] = q.x; lv[i*4+1] = q.y; lv[i*4+2] = q.z; lv[i*4+3] = q.w;
    }
    float mx = -1e30f;
#pragma unroll
    for (int i = 0; i < 16; ++i) mx = fmaxf(mx, lv[i]);
    float ssum = 0.f;
#pragma unroll
    for (int i = 0; i < 16; ++i) { lv[i] = expf(lv[i] - mx); ssum += lv[i]; }
    float sinv = 1.0f / ssum;

    float a = 0.f;
#pragma unroll
    for (int l = 0; l < 4; ++l) {
        float rx = trp[((size_t)r * NL + l) * 2 + 0];
        float ry = trp[((size_t)r * NL + l) * 2 + 1];
        int Hl = Hs[l], Wl = Ws[l], s = Ss[l];
        float fW = (float)Wl, fH = (float)Hl;
#pragma unroll
        for (int p = 0; p < 4; ++p) {
            float ox = offr[((h * NL + l) * NP + p) * 2 + 0];
            float oy = offr[((h * NL + l) * NP + p) * 2 + 1];
            float w = lv[l * 4 + p] * sinv;
            float x = (rx + ox / fW) * fW - 0.5f;
            float y = (ry + oy / fH) * fH - 0.5f;
            float x0 = floorf(x), y0 = floorf(y);
            float sum = 0.f;
#pragma unroll
            for (int dy = 0; dy < 2; ++dy) {
#pragma unroll
                for (int dx = 0; dx < 2; ++dx) {
                    float xi = x0 + dx, yi = y0 + dy;
                    float wgt = (1.0f - fabsf(x - xi)) * (1.0f - fabsf(y - yi));
                    bool valid = (xi >= 0.f) && (xi < fW) && (yi >= 0.f) && (yi < fH);
                    int xic = min(max((int)xi, 0), Wl - 1);
                    int yic = min(max((int)yi, 0), Hl - 1);
                    float v = vb[((size_t)s + yic * Wl + xic) * DH + d];
                    sum += (valid ? wgt : 0.f) * v;
                }
            }
            a += w * sum;
        }
    }
    acc[(size_t)r * C + h * DH + d] = a;
}

// ---------------- residual + LN ----------------
__global__ void k_res_ln(const float* __restrict__ Yin, const float* __restrict__ Xres,
                         const float* __restrict__ g, const float* __restrict__ be,
                         float* __restrict__ out) {
    __shared__ float pr[4];
    int r = blockIdx.x, t = threadIdx.x;
    float v = Yin[(size_t)r * C + t] + Xres[(size_t)r * C + t];
    float mean = block_sum256(v, pr) * (1.0f / C);
    float dv = v - mean;
    float var = block_sum256(dv * dv, pr) * (1.0f / C);
    out[(size_t)r * C + t] = dv * rsqrtf(var + 1e-5f) * g[t] + be[t];
}

__global__ void k_res_ln2(const float* __restrict__ Y0, const float* __restrict__ Y1,
                          const float* __restrict__ Xres,
                          const float* __restrict__ g, const float* __restrict__ be,
                          float* __restrict__ out) {
    __shared__ float pr[4];
    int r = blockIdx.x, t = threadIdx.x;
    float v = Y0[(size_t)r * C + t] + Y1[(size_t)r * C + t] + Xres[(size_t)r * C + t];
    float mean = block_sum256(v, pr) * (1.0f / C);
    float dv = v - mean;
    float var = block_sum256(dv * dv, pr) * (1.0f / C);
    out[(size_t)r * C + t] = dv * rsqrtf(var + 1e-5f) * g[t] + be[t];
}

// ---------------- MFMA flash attention ----------------
// Block = (bh, 64-query tile). 4 waves; wave w owns private key chunks
// k0 = ci*256 + w*64 with private LDS (no barriers in main loop).
// S^T[64k][64q] = mfma(K_frag, Q_frag); online softmax per lane (one q per n-tile);
// P -> bf16 LDS [q][k]; O^T[32d][64q] = mfma(Vt_frag, P_frag). Wave combine at end.
#define NQC3 15   // ceil(900/64)

__global__ __launch_bounds__(256, 1)
void k_attn3(const float* __restrict__ Q, const float* __restrict__ K,
             const float* __restrict__ V, float* __restrict__ O) {
    __shared__ unsigned short sK[4][64 * 72];   // K rows [key][d]
    __shared__ unsigned short sV[4][32 * 72];   // V^T [d][key]
    __shared__ float sPO[4][64 * 36];           // P bf16 [64q][72k] overlaid, then Obuf f32 [64q][36d]
    __shared__ float sWm[4][64], sWl[4][64];

    int blk = blockIdx.x;
    int bh = blk & 31;                 // XCD locality: all q-tiles of a bh share an XCD
    int qc = blk >> 5;
    int b = bh >> 3, h = bh & 7;
    int t = threadIdx.x;
    int w = t >> 6, lane = t & 63;
    int lr = lane & 15, g = lane >> 4;

    const float* Qb = Q + (size_t)bh * LQ * DH;
    const float* Kb = K + (size_t)bh * LQ * DH;
    const float* Vb = V + (size_t)bh * LQ * DH;

    unsigned short* Ks = sK[w];
    unsigned short* Vt = sV[w];
    unsigned short* Ps = (unsigned short*)sPO[w];

    // Q fragments (B operand), 4 n-tiles of 16 q, kept in registers
    bf8_t qf[4];
#pragma unroll
    for (int nt = 0; nt < 4; ++nt) {
        int qg = min(qc * 64 + nt * 16 + lr, LQ - 1);
        const float* qp = Qb + (size_t)qg * DH + g * 8;
        float4 q0 = *(const float4*)qp;
        float4 q1 = *(const float4*)(qp + 4);
        bf8_t f;
        f[0] = (short)f2bf(q0.x); f[1] = (short)f2bf(q0.y); f[2] = (short)f2bf(q0.z); f[3] = (short)f2bf(q0.w);
        f[4] = (short)f2bf(q1.x); f[5] = (short)f2bf(q1.y); f[6] = (short)f2bf(q1.z); f[7] = (short)f2bf(q1.w);
        qf[nt] = f;
    }

    float m[4], l[4];
    f4_t acc[2][4];
#pragma unroll
    for (int nt = 0; nt < 4; ++nt) {
        m[nt] = -3e38f; l[nt] = 0.f;
        acc[0][nt] = (f4_t)0.f; acc[1][nt] = (f4_t)0.f;
    }

    for (int ci = 0; ci < 4; ++ci) {
        int k0 = ci * 256 + w * 64;
        if (k0 >= LQ) break;
        // ---- stage: lane = key k0+lane ----
        int kgl = min(k0 + lane, LQ - 1);
        const float* kr = Kb + (size_t)kgl * DH;
        const float* vr = Vb + (size_t)kgl * DH;
#pragma unroll
        for (int i = 0; i < 4; ++i) {
            float4 a0 = *(const float4*)(kr + i * 8);
            float4 a1 = *(const float4*)(kr + i * 8 + 4);
            us8_t u;
            u[0]=f2bf(a0.x); u[1]=f2bf(a0.y); u[2]=f2bf(a0.z); u[3]=f2bf(a0.w);
            u[4]=f2bf(a1.x); u[5]=f2bf(a1.y); u[6]=f2bf(a1.z); u[7]=f2bf(a1.w);
            *(us8_t*)&Ks[lane * 72 + i * 8] = u;
        }
#pragma unroll
        for (int i = 0; i < 8; ++i) {
            float4 v4 = *(const float4*)(vr + i * 4);
            Vt[(i * 4 + 0) * 72 + lane] = f2bf(v4.x);
            Vt[(i * 4 + 1) * 72 + lane] = f2bf(v4.y);
            Vt[(i * 4 + 2) * 72 + lane] = f2bf(v4.z);
            Vt[(i * 4 + 3) * 72 + lane] = f2bf(v4.w);
        }
        // ---- QK^T: S^T[64k][64q] ----
        bf8_t ka[4];
#pragma unroll
        for (int mt = 0; mt < 4; ++mt)
            ka[mt] = *(const bf8_t*)&Ks[(mt * 16 + lr) * 72 + g * 8];
        f4_t st[4][4];
#pragma unroll
        for (int mt = 0; mt < 4; ++mt)
#pragma unroll
            for (int nt = 0; nt < 4; ++nt)
                st[mt][nt] = __builtin_amdgcn_mfma_f32_16x16x32_bf16(ka[mt], qf[nt], (f4_t)0.f, 0, 0, 0);
        // ---- online softmax + P write ----
#pragma unroll
        for (int nt = 0; nt < 4; ++nt) {
            float sv[4][4];
            float cm = -3e38f;
#pragma unroll
            for (int mt = 0; mt < 4; ++mt)
#pragma unroll
                for (int rr = 0; rr < 4; ++rr) {
                    bool valid = (k0 + mt * 16 + g * 4 + rr) < LQ;
                    float s = valid ? st[mt][nt][rr] : -3e38f;
                    sv[mt][rr] = s;
                    cm = fmaxf(cm, s);
                }
            cm = fmaxf(cm, __shfl_xor(cm, 16, 64));
            cm = fmaxf(cm, __shfl_xor(cm, 32, 64));
            float mn = fmaxf(m[nt], cm);
            float sc = __expf(m[nt] - mn);
            float cs = 0.f;
#pragma unroll
            for (int mt = 0; mt < 4; ++mt) {
                us4_t pk;
#pragma unroll
                for (int rr = 0; rr < 4; ++rr) {
                    float p = (sv[mt][rr] > -1e37f) ? __expf(sv[mt][rr] - mn) : 0.f;
                    cs += p;
                    pk[rr] = f2bf(p);
                }
                *(us4_t*)&Ps[(nt * 16 + lr) * 72 + mt * 16 + g * 4] = pk;
            }
            cs += __shfl_xor(cs, 16, 64);
            cs += __shfl_xor(cs, 32, 64);
            l[nt] = l[nt] * sc + cs;
            m[nt] = mn;
            acc[0][nt] *= sc;
            acc[1][nt] *= sc;
        }
        // ---- PV: O^T[32d][64q] ----
        bf8_t va[2][2];
#pragma unroll
        for (int md = 0; md < 2; ++md)
#pragma unroll
            for (int kt = 0; kt < 2; ++kt)
                va[md][kt] = *(const bf8_t*)&Vt[(md * 16 + lr) * 72 + kt * 32 + g * 8];
#pragma unroll
        for (int nt = 0; nt < 4; ++nt)
#pragma unroll
            for (int kt = 0; kt < 2; ++kt) {
                bf8_t pb = *(const bf8_t*)&Ps[(nt * 16 + lr) * 72 + kt * 32 + g * 8];
                acc[0][nt] = __builtin_amdgcn_mfma_f32_16x16x32_bf16(va[0][kt], pb, acc[0][nt], 0, 0, 0);
                acc[1][nt] = __builtin_amdgcn_mfma_f32_16x16x32_bf16(va[1][kt], pb, acc[1][nt], 0, 0, 0);
            }
    }

    // ---- wave combine ----
    if (g == 0) {
#pragma unroll
        for (int nt = 0; nt < 4; ++nt) {
            sWm[w][nt * 16 + lr] = m[nt];
            sWl[w][nt * 16 + lr] = l[nt];
        }
    }
    __syncthreads();
    float* ob = sPO[w];
#pragma unroll
    for (int nt = 0; nt < 4; ++nt) {
        int q = nt * 16 + lr;
        float M = fmaxf(fmaxf(sWm[0][q], sWm[1][q]), fmaxf(sWm[2][q], sWm[3][q]));
        float fac = __expf(m[nt] - M);
        f4_t v0 = acc[0][nt] * fac;
        f4_t v1 = acc[1][nt] * fac;
        *(f4_t*)&ob[q * 36 + g * 4] = v0;
        *(f4_t*)&ob[q * 36 + 16 + g * 4] = v1;
    }
    __syncthreads();
    {
        int q = t >> 2, d0 = (t & 3) * 8;
        int qglob = qc * 64 + q;
        if (qglob < LQ) {
            float M = fmaxf(fmaxf(sWm[0][q], sWm[1][q]), fmaxf(sWm[2][q], sWm[3][q]));
            float L = 0.f;
#pragma unroll
            for (int w2 = 0; w2 < 4; ++w2) L += sWl[w2][q] * __expf(sWm[w2][q] - M);
            float inv = 1.0f / L;
            f4_t r0 = (f4_t)0.f, r1 = (f4_t)0.f;
#pragma unroll
            for (int w2 = 0; w2 < 4; ++w2) {
                r0 += *(f4_t*)&sPO[w2][q * 36 + d0];
                r1 += *(f4_t*)&sPO[w2][q * 36 + d0 + 4];
            }
            r0 *= inv; r1 *= inv;
            float* op = O + ((size_t)(qglob * BQ + b)) * C + h * 32 + d0;
            *(f4_t*)op = r0;
            *(f4_t*)(op + 4) = r1;
        }
    }
}

// ---------------- launch ----------------
extern "C" void kernel_launch(void* const* d_in, const int* in_sizes, int n_in,
                              void* d_out, int out_size, void* d_ws, size_t ws_size,
                              hipStream_t stream) {
    const float* tgt      = (const float*)d_in[0];
    const float* trp      = (const float*)d_in[1];
    const float* memory   = (const float*)d_in[2];
    const float* vproj_w  = (const float*)d_in[5];  const float* vproj_b  = (const float*)d_in[6];
    const float* off_w    = (const float*)d_in[7];  const float* off_b    = (const float*)d_in[8];
    const float* aw_w     = (const float*)d_in[9];  const float* aw_b     = (const float*)d_in[10];
    const float* oproj_w  = (const float*)d_in[11]; const float* oproj_b  = (const float*)d_in[12];
    const float* ln1_g    = (const float*)d_in[13]; const float* ln1_b    = (const float*)d_in[14];
    const float* sa_in_w  = (const float*)d_in[15]; const float* sa_in_b  = (const float*)d_in[16];
    const float* sa_out_w = (const float*)d_in[17]; const float* sa_out_b = (const float*)d_in[18];
    const float* ln2_g    = (const float*)d_in[19]; const float* ln2_b    = (const float*)d_in[20];
    const float* l1_w     = (const float*)d_in[21]; const float* l1_b     = (const float*)d_in[22];
    const float* l2_w     = (const float*)d_in[23]; const float* l2_b     = (const float*)d_in[24];
    const float* ln3_g    = (const float*)d_in[25]; const float* ln3_b    = (const float*)d_in[26];
    const float* sa3_in_w = (const float*)d_in[27]; const float* sa3_in_b = (const float*)d_in[28];
    const float* sa3_out_w= (const float*)d_in[29]; const float* sa3_out_b= (const float*)d_in[30];
    const float* ln5_g    = (const float*)d_in[31]; const float* ln5_b    = (const float*)d_in[32];
    const float* l31_w    = (const float*)d_in[33]; const float* l31_b    = (const float*)d_in[34];
    const float* l32_w    = (const float*)d_in[35]; const float* l32_b    = (const float*)d_in[36];
    const float* ln33_g   = (const float*)d_in[37]; const float* ln33_b   = (const float*)d_in[38];

    float* ws = (float*)d_ws;
    float* X     = ws;                       // 921,600  (current residual stream, token layout)
    float* value = ws + 921600;              // 18,248,704  [B,H,LV,32]
    float* off   = value + 18248704;         // 921,600
    float* aw    = off + 921600;             // 460,800 (logits)
    float* acc   = aw + 460800;              // 921,600
    // value region reused after sampling is done / between phases:
    float* QKV = value;                      // 2,764,800 (Q|K|V each 921,600)
    float* O   = value + 2764800;            // 921,600
    float* H1  = value + 3686400;            // 7,372,800 (also proj scratch T1)
    float* Y   = value + 11059200;           // 921,600
    float* Y2  = value + 11980800;           // 921,600 (split-K partial)
    float* T1  = H1;                         // proj output scratch (free outside FFN)

    const int NVROWS = BQ * LVTOT;           // 71,284
    dim3 blk(256);
    dim3 gTok(29, 4);                        // 3600-row x 256-col GEMM grid

    // ---- ca: MSDeformAttn ----
    k_mgemm<256, 256, MODE_VALUE><<<dim3((NVROWS + 127) / 128, 4), blk, 0, stream>>>(memory, vproj_w, vproj_b, value, NVROWS);
    k_mgemm<256, 256, MODE_NORMAL><<<gTok, blk, 0, stream>>>(tgt, off_w, off_b, off, NTOK);
    k_mgemm<256, 256, MODE_NORMAL><<<dim3(29, 2), blk, 0, stream>>>(tgt, aw_w, aw_b, aw, NTOK);
    k_sample<<<NTOK, blk, 0, stream>>>(trp, off, aw, value, acc);
    k_mgemm<256, 256, MODE_NORMAL><<<gTok, blk, 0, stream>>>(acc, oproj_w, oproj_b, T1, NTOK);
    k_res_ln<<<NTOK, blk, 0, stream>>>(T1, tgt, ln1_g, ln1_b, X);

    // ---- sa ----
    k_mgemm<256, 256, MODE_QKV><<<dim3(29, 12), blk, 0, stream>>>(X, sa_in_w, sa_in_b, QKV, NTOK);
    k_attn3<<<32 * NQC3, blk, 0, stream>>>(QKV, QKV + 921600, QKV + 1843200, O);
    k_mgemm<256, 256, MODE_NORMAL><<<gTok, blk, 0, stream>>>(O, sa_out_w, sa_out_b, T1, NTOK);
    k_res_ln<<<NTOK, blk, 0, stream>>>(T1, X, ln2_g, ln2_b, X);

    // ---- ffn ----
    k_mgemm<256, 256, MODE_RELU><<<dim3(29, 32), blk, 0, stream>>>(X, l1_w, l1_b, H1, NTOK);
    k_mgemm<1024, 2048, MODE_NORMAL><<<gTok, blk, 0, stream>>>(H1, l2_w, l2_b, Y, NTOK);
    k_mgemm<1024, 2048, MODE_NORMAL><<<gTok, blk, 0, stream>>>(H1 + 1024, l2_w + 1024, (const float*)nullptr, Y2, NTOK);
    k_res_ln2<<<NTOK, blk, 0, stream>>>(Y, Y2, X, ln3_g, ln3_b, X);

    // ---- sa3 ----
    k_mgemm<256, 256, MODE_QKV><<<dim3(29, 12), blk, 0, stream>>>(X, sa3_in_w, sa3_in_b, QKV, NTOK);
    k_attn3<<<32 * NQC3, blk, 0, stream>>>(QKV, QKV + 921600, QKV + 1843200, O);
    k_mgemm<256, 256, MODE_NORMAL><<<gTok, blk, 0, stream>>>(O, sa3_out_w, sa3_out_b, T1, NTOK);
    k_res_ln<<<NTOK, blk, 0, stream>>>(T1, X, ln5_g, ln5_b, X);

    // ---- ffn3 ----
    k_mgemm<256, 256, MODE_RELU><<<dim3(29, 32), blk, 0, stream>>>(X, l31_w, l31_b, H1, NTOK);
    k_mgemm<1024, 2048, MODE_NORMAL><<<gTok, blk, 0, stream>>>(H1, l32_w, l32_b, Y, NTOK);
    k_mgemm<1024, 2048, MODE_NORMAL><<<gTok, blk, 0, stream>>>(H1 + 1024, l32_w + 1024, (const float*)nullptr, Y2, NTOK);
    k_res_ln2<<<NTOK, blk, 0, stream>>>(Y, Y2, X, ln33_g, ln33_b, (float*)d_out);
}

// Round 7
// 492.640 us; speedup vs baseline: 6.0832x; 1.1941x over previous
//
#include <hip/hip_runtime.h>
#include <math.h>

#define C 256
#define DH 32
#define NH 8
#define NL 4
#define NP 4
#define BQ 4
#define LQ 900
#define LVTOT 17821
#define DFFN 2048
#define NTOK (BQ*LQ)          // 3600 token rows, token index t = lq*B + b

typedef __attribute__((ext_vector_type(8))) short bf8_t;    // 8 bf16 (4 VGPRs)
typedef __attribute__((ext_vector_type(4))) float f4_t;     // MFMA acc
typedef __attribute__((ext_vector_type(8))) unsigned short us8_t;
typedef __attribute__((ext_vector_type(4))) unsigned short us4_t;

// ---------------- helpers ----------------
__device__ __forceinline__ float block_sum256(float v, float* pr) {
    int t = threadIdx.x, lane = t & 63, wv = t >> 6;
#pragma unroll
    for (int o = 32; o > 0; o >>= 1) v += __shfl_down(v, o, 64);
    if (lane == 0) pr[wv] = v;
    __syncthreads();
    float r = pr[0] + pr[1] + pr[2] + pr[3];
    __syncthreads();
    return r;
}

__device__ __forceinline__ unsigned short f2bf(float f) {
    unsigned int u = __float_as_uint(f);
    u += 0x7fffu + ((u >> 16) & 1u);   // round-to-nearest-even
    return (unsigned short)(u >> 16);
}
__device__ __forceinline__ float b2f(unsigned short u) {
    return __uint_as_float(((unsigned int)u) << 16);
}

// ---------------- bf16 MFMA GEMM: Y = act(A @ W^T + b) ----------------
// A: [nrows][KS] fp32 (AB=0) or bf16 (AB=1); W: [OC][KS] fp32.
// Output f32 (OB=0) or bf16 (OB=1). Tile 128x64, 4 waves 2x2, K-step 32.
enum { MODE_NORMAL = 0, MODE_RELU = 1, MODE_VALUE = 2, MODE_QKV = 3 };

#define LDP 72   // LDS row stride in bf16 elems (144 B = 9*16B: aligned b128)

template<int K, int KS, int MODE, int AB, int OB>
__global__ void k_mgemm(const void* __restrict__ A_, const float* __restrict__ W,
                        const float* __restrict__ bias, void* __restrict__ Y_, int nrows) {
    __shared__ unsigned short Ash[128 * LDP];
    __shared__ unsigned short Bsh[64 * LDP];
    int t = threadIdx.x;
    int lane = t & 63, w = t >> 6;
    int wm = w & 1, wn = w >> 1;
    int r0 = blockIdx.x * 128;
    int c0 = blockIdx.y * 64;

    f4_t acc[4][2];
#pragma unroll
    for (int mt = 0; mt < 4; ++mt)
#pragma unroll
        for (int nt = 0; nt < 2; ++nt) acc[mt][nt] = (f4_t)0.f;

    int arow = t >> 1;
    int akoff = (t & 1) * 16;
    int asrc = min(r0 + arow, nrows - 1);
    const float* aptrf = (const float*)A_ + (size_t)asrc * KS + akoff;
    const unsigned short* aptrh = (const unsigned short*)A_ + (size_t)asrc * KS + akoff;
    unsigned short* adst = &Ash[arow * LDP + akoff];

    int brow = t >> 2;
    int bkoff = (t & 3) * 8;
    const float* bptr = W + (size_t)(c0 + brow) * KS + bkoff;
    unsigned short* bdst = &Bsh[brow * LDP + bkoff];

    int lr = lane & 15, kg = lane >> 4;

    for (int k0 = 0; k0 < K; k0 += 32) {
        __syncthreads();
        if (AB) {
            *(us8_t*)(adst) = *(const us8_t*)(aptrh + k0);
            *(us8_t*)(adst + 8) = *(const us8_t*)(aptrh + k0 + 8);
        } else {
            float4 av0 = *(const float4*)(aptrf + k0);
            float4 av1 = *(const float4*)(aptrf + k0 + 4);
            float4 av2 = *(const float4*)(aptrf + k0 + 8);
            float4 av3 = *(const float4*)(aptrf + k0 + 12);
            us8_t u0, u1;
            u0[0]=f2bf(av0.x); u0[1]=f2bf(av0.y); u0[2]=f2bf(av0.z); u0[3]=f2bf(av0.w);
            u0[4]=f2bf(av1.x); u0[5]=f2bf(av1.y); u0[6]=f2bf(av1.z); u0[7]=f2bf(av1.w);
            u1[0]=f2bf(av2.x); u1[1]=f2bf(av2.y); u1[2]=f2bf(av2.z); u1[3]=f2bf(av2.w);
            u1[4]=f2bf(av3.x); u1[5]=f2bf(av3.y); u1[6]=f2bf(av3.z); u1[7]=f2bf(av3.w);
            *(us8_t*)(adst) = u0;
            *(us8_t*)(adst + 8) = u1;
        }
        {
            float4 bv0 = *(const float4*)(bptr + k0);
            float4 bv1 = *(const float4*)(bptr + k0 + 4);
            us8_t u;
            u[0]=f2bf(bv0.x); u[1]=f2bf(bv0.y); u[2]=f2bf(bv0.z); u[3]=f2bf(bv0.w);
            u[4]=f2bf(bv1.x); u[5]=f2bf(bv1.y); u[6]=f2bf(bv1.z); u[7]=f2bf(bv1.w);
            *(us8_t*)(bdst) = u;
        }
        __syncthreads();

        bf8_t afr[4], bfr[2];
#pragma unroll
        for (int mt = 0; mt < 4; ++mt)
            afr[mt] = *(const bf8_t*)&Ash[(wm * 64 + mt * 16 + lr) * LDP + kg * 8];
#pragma unroll
        for (int nt = 0; nt < 2; ++nt)
            bfr[nt] = *(const bf8_t*)&Bsh[(wn * 32 + nt * 16 + lr) * LDP + kg * 8];
#pragma unroll
        for (int mt = 0; mt < 4; ++mt)
#pragma unroll
            for (int nt = 0; nt < 2; ++nt)
                acc[mt][nt] = __builtin_amdgcn_mfma_f32_16x16x32_bf16(afr[mt], bfr[nt], acc[mt][nt], 0, 0, 0);
    }

#pragma unroll
    for (int mt = 0; mt < 4; ++mt) {
#pragma unroll
        for (int nt = 0; nt < 2; ++nt) {
            int col = c0 + wn * 32 + nt * 16 + lr;
            float b0 = bias ? bias[col] : 0.f;
#pragma unroll
            for (int rr = 0; rr < 4; ++rr) {
                int row = r0 + wm * 64 + mt * 16 + kg * 4 + rr;
                if (row >= nrows) continue;
                float v = acc[mt][nt][rr] + b0;
                size_t idx;
                if (MODE == MODE_NORMAL) {
                    idx = (size_t)row * gridDim.y * 64 + col;
                } else if (MODE == MODE_RELU) {
                    v = fmaxf(v, 0.f);
                    idx = (size_t)row * gridDim.y * 64 + col;
                } else if (MODE == MODE_VALUE) {
                    int lv = row >> 2, b = row & 3;
                    int h = col >> 5, d = col & 31;
                    idx = (((size_t)b * NH + h) * LVTOT + lv) * DH + d;
                } else { // MODE_QKV
                    int lq = row >> 2, b = row & 3;
                    int part = col >> 8, cc = col & 255;
                    int h = cc >> 5, d = cc & 31;
                    if (part == 0) v *= 0.17677669529663687f;  // 1/sqrt(32)
                    idx = (size_t)part * (BQ * NH * LQ * DH) + (((size_t)b * NH + h) * LQ + lq) * DH + d;
                }
                if (OB) ((unsigned short*)Y_)[idx] = f2bf(v);
                else    ((float*)Y_)[idx] = v;
            }
        }
    }
}

// ---------------- deformable sampling (aw softmax folded in; bf16 value) ----------------
__global__ void k_sample(const float* __restrict__ trp, const float* __restrict__ off,
                         const float* __restrict__ awl, const unsigned short* __restrict__ value,
                         float* __restrict__ acc) {
    int r = blockIdx.x;
    int b = r & 3;
    int t = threadIdx.x;
    int h = t >> 5, d = t & 31;
    const int Hs[4] = {100, 50, 25, 13};
    const int Ws[4] = {134, 67, 34, 17};
    const int Ss[4] = {0, 13400, 16750, 17600};
    const float* offr = off + (size_t)r * C;
    const unsigned short* vb = value + ((size_t)b * NH + h) * (size_t)LVTOT * DH;

    const float* lg = awl + (size_t)r * 128 + h * 16;
    float lv[16];
#pragma unroll
    for (int i = 0; i < 4; ++i) {
        float4 q = *(const float4*)(lg + i * 4);
        lv[i*4+0] = q.x; lv[i*4+1] = q.y; lv[i*4+2] = q.z; lv[i*4+3] = q.w;
    }
    float mx = -1e30f;
#pragma unroll
    for (int i = 0; i < 16; ++i) mx = fmaxf(mx, lv[i]);
    float ssum = 0.f;
#pragma unroll
    for (int i = 0; i < 16; ++i) { lv[i] = __expf(lv[i] - mx); ssum += lv[i]; }
    float sinv = 1.0f / ssum;

    float a = 0.f;
#pragma unroll
    for (int l = 0; l < 4; ++l) {
        float rx = trp[((size_t)r * NL + l) * 2 + 0];
        float ry = trp[((size_t)r * NL + l) * 2 + 1];
        int Hl = Hs[l], Wl = Ws[l], s = Ss[l];
        float fW = (float)Wl, fH = (float)Hl;
#pragma unroll
        for (int p = 0; p < 4; ++p) {
            float ox = offr[((h * NL + l) * NP + p) * 2 + 0];
            float oy = offr[((h * NL + l) * NP + p) * 2 + 1];
            float w = lv[l * 4 + p] * sinv;
            float x = (rx + ox / fW) * fW - 0.5f;
            float y = (ry + oy / fH) * fH - 0.5f;
            float x0 = floorf(x), y0 = floorf(y);
            float sum = 0.f;
#pragma unroll
            for (int dy = 0; dy < 2; ++dy) {
#pragma unroll
                for (int dx = 0; dx < 2; ++dx) {
                    float xi = x0 + dx, yi = y0 + dy;
                    float wgt = (1.0f - fabsf(x - xi)) * (1.0f - fabsf(y - yi));
                    bool valid = (xi >= 0.f) && (xi < fW) && (yi >= 0.f) && (yi < fH);
                    int xic = min(max((int)xi, 0), Wl - 1);
                    int yic = min(max((int)yi, 0), Hl - 1);
                    float v = b2f(vb[((size_t)s + yic * Wl + xic) * DH + d]);
                    sum += (valid ? wgt : 0.f) * v;
                }
            }
            a += w * sum;
        }
    }
    acc[(size_t)r * C + h * DH + d] = a;
}

// ---------------- residual + LN ----------------
__global__ void k_res_ln(const float* __restrict__ Yin, const float* __restrict__ Xres,
                         const float* __restrict__ g, const float* __restrict__ be,
                         float* __restrict__ out) {
    __shared__ float pr[4];
    int r = blockIdx.x, t = threadIdx.x;
    float v = Yin[(size_t)r * C + t] + Xres[(size_t)r * C + t];
    float mean = block_sum256(v, pr) * (1.0f / C);
    float dv = v - mean;
    float var = block_sum256(dv * dv, pr) * (1.0f / C);
    out[(size_t)r * C + t] = dv * rsqrtf(var + 1e-5f) * g[t] + be[t];
}

__global__ void k_res_ln2(const float* __restrict__ Y0, const float* __restrict__ Y1,
                          const float* __restrict__ Xres,
                          const float* __restrict__ g, const float* __restrict__ be,
                          float* __restrict__ out) {
    __shared__ float pr[4];
    int r = blockIdx.x, t = threadIdx.x;
    float v = Y0[(size_t)r * C + t] + Y1[(size_t)r * C + t] + Xres[(size_t)r * C + t];
    float mean = block_sum256(v, pr) * (1.0f / C);
    float dv = v - mean;
    float var = block_sum256(dv * dv, pr) * (1.0f / C);
    out[(size_t)r * C + t] = dv * rsqrtf(var + 1e-5f) * g[t] + be[t];
}

// ---------------- MFMA flash attention (bf16 Q/K/V/O) ----------------
#define NQC3 15   // ceil(900/64)

__global__ __launch_bounds__(256, 1)
void k_attn3(const unsigned short* __restrict__ Q, const unsigned short* __restrict__ K,
             const unsigned short* __restrict__ V, unsigned short* __restrict__ O) {
    __shared__ unsigned short sK[4][64 * 72];   // K rows [key][d]
    __shared__ unsigned short sV[4][32 * 72];   // V^T [d][key]
    __shared__ float sPO[4][64 * 36];           // P bf16 [64q][72k] overlaid, then Obuf f32 [64q][36d]
    __shared__ float sWm[4][64], sWl[4][64];

    int blk = blockIdx.x;
    int bh = blk & 31;                 // XCD locality
    int qc = blk >> 5;
    int b = bh >> 3, h = bh & 7;
    int t = threadIdx.x;
    int w = t >> 6, lane = t & 63;
    int lr = lane & 15, g = lane >> 4;

    const unsigned short* Qb = Q + (size_t)bh * LQ * DH;
    const unsigned short* Kb = K + (size_t)bh * LQ * DH;
    const unsigned short* Vb = V + (size_t)bh * LQ * DH;

    unsigned short* Ks = sK[w];
    unsigned short* Vt = sV[w];
    unsigned short* Ps = (unsigned short*)sPO[w];

    bf8_t qf[4];
#pragma unroll
    for (int nt = 0; nt < 4; ++nt) {
        int qg = min(qc * 64 + nt * 16 + lr, LQ - 1);
        qf[nt] = *(const bf8_t*)(Qb + (size_t)qg * DH + g * 8);
    }

    float m[4], l[4];
    f4_t acc[2][4];
#pragma unroll
    for (int nt = 0; nt < 4; ++nt) {
        m[nt] = -3e38f; l[nt] = 0.f;
        acc[0][nt] = (f4_t)0.f; acc[1][nt] = (f4_t)0.f;
    }

    for (int ci = 0; ci < 4; ++ci) {
        int k0 = ci * 256 + w * 64;
        if (k0 >= LQ) break;
        int kgl = min(k0 + lane, LQ - 1);
        const unsigned short* kr = Kb + (size_t)kgl * DH;
        const unsigned short* vr = Vb + (size_t)kgl * DH;
#pragma unroll
        for (int i = 0; i < 4; ++i)
            *(us8_t*)&Ks[lane * 72 + i * 8] = *(const us8_t*)(kr + i * 8);
#pragma unroll
        for (int i = 0; i < 4; ++i) {
            us8_t v8 = *(const us8_t*)(vr + i * 8);
#pragma unroll
            for (int j = 0; j < 8; ++j)
                Vt[(i * 8 + j) * 72 + lane] = v8[j];
        }
        // ---- QK^T: S^T[64k][64q] ----
        bf8_t ka[4];
#pragma unroll
        for (int mt = 0; mt < 4; ++mt)
            ka[mt] = *(const bf8_t*)&Ks[(mt * 16 + lr) * 72 + g * 8];
        f4_t st[4][4];
#pragma unroll
        for (int mt = 0; mt < 4; ++mt)
#pragma unroll
            for (int nt = 0; nt < 4; ++nt)
                st[mt][nt] = __builtin_amdgcn_mfma_f32_16x16x32_bf16(ka[mt], qf[nt], (f4_t)0.f, 0, 0, 0);
        // ---- online softmax + P write ----
#pragma unroll
        for (int nt = 0; nt < 4; ++nt) {
            float sv[4][4];
            float cm = -3e38f;
#pragma unroll
            for (int mt = 0; mt < 4; ++mt)
#pragma unroll
                for (int rr = 0; rr < 4; ++rr) {
                    bool valid = (k0 + mt * 16 + g * 4 + rr) < LQ;
                    float s = valid ? st[mt][nt][rr] : -3e38f;
                    sv[mt][rr] = s;
                    cm = fmaxf(cm, s);
                }
            cm = fmaxf(cm, __shfl_xor(cm, 16, 64));
            cm = fmaxf(cm, __shfl_xor(cm, 32, 64));
            float mn = fmaxf(m[nt], cm);
            float sc = __expf(m[nt] - mn);
            float cs = 0.f;
#pragma unroll
            for (int mt = 0; mt < 4; ++mt) {
                us4_t pk;
#pragma unroll
                for (int rr = 0; rr < 4; ++rr) {
                    float p = (sv[mt][rr] > -1e37f) ? __expf(sv[mt][rr] - mn) : 0.f;
                    cs += p;
                    pk[rr] = f2bf(p);
                }
                *(us4_t*)&Ps[(nt * 16 + lr) * 72 + mt * 16 + g * 4] = pk;
            }
            cs += __shfl_xor(cs, 16, 64);
            cs += __shfl_xor(cs, 32, 64);
            l[nt] = l[nt] * sc + cs;
            m[nt] = mn;
            acc[0][nt] *= sc;
            acc[1][nt] *= sc;
        }
        // ---- PV: O^T[32d][64q] ----
        bf8_t va[2][2];
#pragma unroll
        for (int md = 0; md < 2; ++md)
#pragma unroll
            for (int kt = 0; kt < 2; ++kt)
                va[md][kt] = *(const bf8_t*)&Vt[(md * 16 + lr) * 72 + kt * 32 + g * 8];
#pragma unroll
        for (int nt = 0; nt < 4; ++nt)
#pragma unroll
            for (int kt = 0; kt < 2; ++kt) {
                bf8_t pb = *(const bf8_t*)&Ps[(nt * 16 + lr) * 72 + kt * 32 + g * 8];
                acc[0][nt] = __builtin_amdgcn_mfma_f32_16x16x32_bf16(va[0][kt], pb, acc[0][nt], 0, 0, 0);
                acc[1][nt] = __builtin_amdgcn_mfma_f32_16x16x32_bf16(va[1][kt], pb, acc[1][nt], 0, 0, 0);
            }
    }

    // ---- wave combine ----
    if (g == 0) {
#pragma unroll
        for (int nt = 0; nt < 4; ++nt) {
            sWm[w][nt * 16 + lr] = m[nt];
            sWl[w][nt * 16 + lr] = l[nt];
        }
    }
    __syncthreads();
    float* ob = sPO[w];
#pragma unroll
    for (int nt = 0; nt < 4; ++nt) {
        int q = nt * 16 + lr;
        float M = fmaxf(fmaxf(sWm[0][q], sWm[1][q]), fmaxf(sWm[2][q], sWm[3][q]));
        float fac = __expf(m[nt] - M);
        f4_t v0 = acc[0][nt] * fac;
        f4_t v1 = acc[1][nt] * fac;
        *(f4_t*)&ob[q * 36 + g * 4] = v0;
        *(f4_t*)&ob[q * 36 + 16 + g * 4] = v1;
    }
    __syncthreads();
    {
        int q = t >> 2, d0 = (t & 3) * 8;
        int qglob = qc * 64 + q;
        if (qglob < LQ) {
            float M = fmaxf(fmaxf(sWm[0][q], sWm[1][q]), fmaxf(sWm[2][q], sWm[3][q]));
            float L = 0.f;
#pragma unroll
            for (int w2 = 0; w2 < 4; ++w2) L += sWl[w2][q] * __expf(sWm[w2][q] - M);
            float inv = 1.0f / L;
            f4_t r0 = (f4_t)0.f, r1 = (f4_t)0.f;
#pragma unroll
            for (int w2 = 0; w2 < 4; ++w2) {
                r0 += *(f4_t*)&sPO[w2][q * 36 + d0];
                r1 += *(f4_t*)&sPO[w2][q * 36 + d0 + 4];
            }
            r0 *= inv; r1 *= inv;
            us8_t u;
#pragma unroll
            for (int j = 0; j < 4; ++j) { u[j] = f2bf(r0[j]); u[4 + j] = f2bf(r1[j]); }
            *(us8_t*)(O + ((size_t)(qglob * BQ + b)) * C + h * 32 + d0) = u;
        }
    }
}

// ---------------- launch ----------------
extern "C" void kernel_launch(void* const* d_in, const int* in_sizes, int n_in,
                              void* d_out, int out_size, void* d_ws, size_t ws_size,
                              hipStream_t stream) {
    const float* tgt      = (const float*)d_in[0];
    const float* trp      = (const float*)d_in[1];
    const float* memory   = (const float*)d_in[2];
    const float* vproj_w  = (const float*)d_in[5];  const float* vproj_b  = (const float*)d_in[6];
    const float* off_w    = (const float*)d_in[7];  const float* off_b    = (const float*)d_in[8];
    const float* aw_w     = (const float*)d_in[9];  const float* aw_b     = (const float*)d_in[10];
    const float* oproj_w  = (const float*)d_in[11]; const float* oproj_b  = (const float*)d_in[12];
    const float* ln1_g    = (const float*)d_in[13]; const float* ln1_b    = (const float*)d_in[14];
    const float* sa_in_w  = (const float*)d_in[15]; const float* sa_in_b  = (const float*)d_in[16];
    const float* sa_out_w = (const float*)d_in[17]; const float* sa_out_b = (const float*)d_in[18];
    const float* ln2_g    = (const float*)d_in[19]; const float* ln2_b    = (const float*)d_in[20];
    const float* l1_w     = (const float*)d_in[21]; const float* l1_b     = (const float*)d_in[22];
    const float* l2_w     = (const float*)d_in[23]; const float* l2_b     = (const float*)d_in[24];
    const float* ln3_g    = (const float*)d_in[25]; const float* ln3_b    = (const float*)d_in[26];
    const float* sa3_in_w = (const float*)d_in[27]; const float* sa3_in_b = (const float*)d_in[28];
    const float* sa3_out_w= (const float*)d_in[29]; const float* sa3_out_b= (const float*)d_in[30];
    const float* ln5_g    = (const float*)d_in[31]; const float* ln5_b    = (const float*)d_in[32];
    const float* l31_w    = (const float*)d_in[33]; const float* l31_b    = (const float*)d_in[34];
    const float* l32_w    = (const float*)d_in[35]; const float* l32_b    = (const float*)d_in[36];
    const float* ln33_g   = (const float*)d_in[37]; const float* ln33_b   = (const float*)d_in[38];

    float* ws = (float*)d_ws;
    float* X              = ws;                                    // 921,600 f32
    unsigned short* valueU= (unsigned short*)(ws + 921600);        // 18,248,704 bf16
    float* off            = ws + 10045952;                         // 921,600 f32
    float* aw             = ws + 10967552;                         // 460,800 f32
    float* acc            = ws + 11428352;                         // 921,600 f32
    unsigned short* QKVu  = (unsigned short*)(ws + 12349952);      // 2,764,800 bf16
    unsigned short* Ou    = (unsigned short*)(ws + 13732352);      // 921,600 bf16
    unsigned short* H1u   = (unsigned short*)(ws + 14193152);      // 7,372,800 bf16
    float* Y              = ws + 17879552;                         // 921,600 f32
    float* Y2             = ws + 18801152;                         // 921,600 f32
    float* T1             = ws + 19722752;                         // 921,600 f32

    const int NVROWS = BQ * LVTOT;           // 71,284
    dim3 blk(256);
    dim3 gTok(29, 4);

    // ---- ca: MSDeformAttn ----
    k_mgemm<256, 256, MODE_VALUE, 0, 1><<<dim3((NVROWS + 127) / 128, 4), blk, 0, stream>>>(memory, vproj_w, vproj_b, valueU, NVROWS);
    k_mgemm<256, 256, MODE_NORMAL, 0, 0><<<gTok, blk, 0, stream>>>(tgt, off_w, off_b, off, NTOK);
    k_mgemm<256, 256, MODE_NORMAL, 0, 0><<<dim3(29, 2), blk, 0, stream>>>(tgt, aw_w, aw_b, aw, NTOK);
    k_sample<<<NTOK, blk, 0, stream>>>(trp, off, aw, valueU, acc);
    k_mgemm<256, 256, MODE_NORMAL, 0, 0><<<gTok, blk, 0, stream>>>(acc, oproj_w, oproj_b, T1, NTOK);
    k_res_ln<<<NTOK, blk, 0, stream>>>(T1, tgt, ln1_g, ln1_b, X);

    // ---- sa ----
    k_mgemm<256, 256, MODE_QKV, 0, 1><<<dim3(29, 12), blk, 0, stream>>>(X, sa_in_w, sa_in_b, QKVu, NTOK);
    k_attn3<<<32 * NQC3, blk, 0, stream>>>(QKVu, QKVu + 921600, QKVu + 1843200, Ou);
    k_mgemm<256, 256, MODE_NORMAL, 1, 0><<<gTok, blk, 0, stream>>>(Ou, sa_out_w, sa_out_b, T1, NTOK);
    k_res_ln<<<NTOK, blk, 0, stream>>>(T1, X, ln2_g, ln2_b, X);

    // ---- ffn ----
    k_mgemm<256, 256, MODE_RELU, 0, 1><<<dim3(29, 32), blk, 0, stream>>>(X, l1_w, l1_b, H1u, NTOK);
    k_mgemm<1024, 2048, MODE_NORMAL, 1, 0><<<gTok, blk, 0, stream>>>(H1u, l2_w, l2_b, Y, NTOK);
    k_mgemm<1024, 2048, MODE_NORMAL, 1, 0><<<gTok, blk, 0, stream>>>(H1u + 1024, l2_w + 1024, (const float*)nullptr, Y2, NTOK);
    k_res_ln2<<<NTOK, blk, 0, stream>>>(Y, Y2, X, ln3_g, ln3_b, X);

    // ---- sa3 ----
    k_mgemm<256, 256, MODE_QKV, 0, 1><<<dim3(29, 12), blk, 0, stream>>>(X, sa3_in_w, sa3_in_b, QKVu, NTOK);
    k_attn3<<<32 * NQC3, blk, 0, stream>>>(QKVu, QKVu + 921600, QKVu + 1843200, Ou);
    k_mgemm<256, 256, MODE_NORMAL, 1, 0><<<gTok, blk, 0, stream>>>(Ou, sa3_out_w, sa3_out_b, T1, NTOK);
    k_res_ln<<<NTOK, blk, 0, stream>>>(T1, X, ln5_g, ln5_b, X);

    // ---- ffn3 ----
    k_mgemm<256, 256, MODE_RELU, 0, 1><<<dim3(29, 32), blk, 0, stream>>>(X, l31_w, l31_b, H1u, NTOK);
    k_mgemm<1024, 2048, MODE_NORMAL, 1, 0><<<gTok, blk, 0, stream>>>(H1u, l32_w, l32_b, Y, NTOK);
    k_mgemm<1024, 2048, MODE_NORMAL, 1, 0><<<gTok, blk, 0, stream>>>(H1u + 1024, l32_w + 1024, (const float*)nullptr, Y2, NTOK);
    k_res_ln2<<<NTOK, blk, 0, stream>>>(Y, Y2, X, ln33_g, ln33_b, (float*)d_out);
}